// Round 11
// baseline (1052.389 us; speedup 1.0000x reference)
//
#include <hip/hip_runtime.h>
#include <cmath>
#include <cstdint>
#include <cstddef>

namespace {
constexpr int kB = 4;
constexpr int kS = 2048;
constexpr int kD = 768;
constexpr int kH = 12;
constexpr int kHD = 64;
constexpr int k3D = 3 * kD;   // 2304
constexpr float kNeg = -1000000000.0f;
constexpr float kDelta = 0.25f;   // rescue margin >= 2 * bf16 dot error bound
}

// Faithful fp32 masking affine: s = a + NEG*(1-a), no fma contraction so the
// rounding sequence matches numpy's elementwise ops. (Identical to rounds 1-10.)
__device__ __forceinline__ float mask_affine(float a) {
#pragma clang fp contract(off)
    const float u = 1.0f - a;
    return a + kNeg * u;
}

__device__ __forceinline__ short bf16rne_s(float f) {
    uint32_t u = __builtin_bit_cast(uint32_t, f);
    u += 0x7FFFu + ((u >> 16) & 1u);
    return (short)(u >> 16);
}
__device__ __forceinline__ float bf16tof(short h) {
    const uint32_t u = ((uint32_t)(unsigned short)h) << 16;
    return __builtin_bit_cast(float, u);
}

// ---------------------------------------------------------------------------
// FUSED projection kernel: even blocks run the EXACT fp32 QK GEMM (r7/r10
// geometry, bit-identical arithmetic — selection-critical), odd blocks run the
// staged-split bf16 MFMA V GEMM (r10 code). QK is VALU-bound, V is MFMA-bound;
// co-residency overlaps the two pipes (m114: time ~ max, not sum).
// ---------------------------------------------------------------------------
__global__ __launch_bounds__(256)
void fused_proj_kernel(const float* __restrict__ x,
                       const float* __restrict__ W_qkv,
                       const float* __restrict__ b_qkv,
                       float* __restrict__ qkv)
{
    using f32x4 = __attribute__((ext_vector_type(4))) float;
    using s16x8 = __attribute__((ext_vector_type(8))) short;
    __shared__ __align__(16) char smem[51200];

    const int id = blockIdx.x;
    const int tid = threadIdx.x;

    if ((id & 1) == 0) {
        // ---------------- QK path: BM=128 BN=128 BK=16 TM=8 TN=8 ----------
        const int q = id >> 1;                    // 0..767
        const int bx = q % 12, by = q / 12;       // N=1536 -> 12 col blocks
        const int m0 = by * 128, n0 = bx * 128;
        const int tx = tid % 16, ty = tid / 16;

        float* As = (float*)smem;                 // [2][16][132]
        float* Bs = (float*)(smem + 16896);       // [2][16][132]

        float4 pa[2], pb[2];
        auto load_tiles = [&](int k0) {
#pragma unroll
            for (int it = 0; it < 2; ++it) {
                const int e = (tid + it * 256) * 4;
                const int row = e / 16, col = e % 16;
                pa[it] = *reinterpret_cast<const float4*>(
                    &x[(size_t)(m0 + row) * kD + (k0 + col)]);
            }
#pragma unroll
            for (int it = 0; it < 2; ++it) {
                const int e = (tid + it * 256) * 4;
                const int row = e / 128, col = e % 128;
                pb[it] = *reinterpret_cast<const float4*>(
                    &W_qkv[(size_t)(k0 + row) * k3D + (n0 + col)]);
            }
        };
        auto commit = [&](int buf) {
#pragma unroll
            for (int it = 0; it < 2; ++it) {
                const int e = (tid + it * 256) * 4;
                const int row = e / 16, col = e % 16;
                As[(buf * 16 + col + 0) * 132 + row] = pa[it].x;
                As[(buf * 16 + col + 1) * 132 + row] = pa[it].y;
                As[(buf * 16 + col + 2) * 132 + row] = pa[it].z;
                As[(buf * 16 + col + 3) * 132 + row] = pa[it].w;
            }
#pragma unroll
            for (int it = 0; it < 2; ++it) {
                const int e = (tid + it * 256) * 4;
                const int row = e / 128, col = e % 128;
                const int g = col / 8, off = col % 8;
                *reinterpret_cast<float4*>(
                    &Bs[(buf * 16 + g) * 132 + row * 8 + off]) = pb[it];
            }
        };

        float acc[8][8];
#pragma unroll
        for (int i = 0; i < 8; ++i)
#pragma unroll
            for (int j = 0; j < 8; ++j) acc[i][j] = 0.0f;

        load_tiles(0);
        commit(0);
        load_tiles(16);
        __syncthreads();

        int cur = 0;
        for (int k0 = 0; k0 < kD; k0 += 16) {
            const bool has_next = (k0 + 16 < kD);
            if (has_next) {
                commit(cur ^ 1);
                if (k0 + 32 < kD) load_tiles(k0 + 32);
            }
#pragma unroll
            for (int kk = 0; kk < 16; ++kk) {
                float a[8], b[8];
#pragma unroll
                for (int i = 0; i < 8; i += 4) {
                    const float4 v = *reinterpret_cast<const float4*>(
                        &As[(cur * 16 + kk) * 132 + ty * 8 + i]);
                    a[i] = v.x; a[i + 1] = v.y; a[i + 2] = v.z; a[i + 3] = v.w;
                }
#pragma unroll
                for (int j = 0; j < 8; j += 4) {
                    const float4 v = *reinterpret_cast<const float4*>(
                        &Bs[(cur * 16 + tx) * 132 + kk * 8 + j]);
                    b[j] = v.x; b[j + 1] = v.y; b[j + 2] = v.z; b[j + 3] = v.w;
                }
#pragma unroll
                for (int i = 0; i < 8; ++i)
#pragma unroll
                    for (int j = 0; j < 8; ++j)
                        acc[i][j] = fmaf(a[i], b[j], acc[i][j]);
            }
            if (has_next) __syncthreads();
            cur ^= 1;
        }

#pragma unroll
        for (int i = 0; i < 8; ++i) {
            const int m = m0 + ty * 8 + i;
#pragma unroll
            for (int j = 0; j < 8; ++j) {
                const int n = n0 + tx * 8 + j;
                qkv[(size_t)m * k3D + n] = acc[i][j] + b_qkv[n];
            }
        }
    } else {
        // ---------------- V path: BM=128 BN=64 BK=32, staged-split bf16 ----
        const int v = id >> 1;                    // 0..767
        const int bx = v % 12, by = v / 12;       // N=768 -> 12 col blocks
        const int m0 = by * 128, n0 = bx * 64;
        const int wave = tid >> 6, lane = tid & 63;
        const int jq = lane & 15, hi = lane >> 4;
        const float* Bm = W_qkv + 2 * kD;
        const float* bias = b_qkv + 2 * kD;
        float* C = qkv + 2 * kD;

        unsigned short* Ah = (unsigned short*)smem;            // [2][128][40]
        unsigned short* Al = (unsigned short*)(smem + 20480);  // [2][128][40]
        unsigned short* Bh = (unsigned short*)(smem + 40960);  // [2][64][40]

        float4 pa[4], pb[2];
        auto load_tiles = [&](int k0) {
#pragma unroll
            for (int it = 0; it < 4; ++it) {
                const int e = (tid + it * 256) * 4;
                const int row = e / 32, col = e % 32;
                pa[it] = *reinterpret_cast<const float4*>(
                    &x[(size_t)(m0 + row) * kD + (k0 + col)]);
            }
#pragma unroll
            for (int it = 0; it < 2; ++it) {
                const int e = (tid + it * 256) * 4;
                const int krow = e / 64, ncol = e % 64;
                pb[it] = *reinterpret_cast<const float4*>(
                    &Bm[(size_t)(k0 + krow) * k3D + (n0 + ncol)]);
            }
        };
        auto commit = [&](int buf) {
#pragma unroll
            for (int it = 0; it < 4; ++it) {
                const int e = (tid + it * 256) * 4;
                const int row = e / 32, col = e % 32;
                const float vv[4] = {pa[it].x, pa[it].y, pa[it].z, pa[it].w};
                ushort4 uh, ul;
                unsigned short* ph = &uh.x;
                unsigned short* pl = &ul.x;
#pragma unroll
                for (int r = 0; r < 4; ++r) {
                    const short hb = bf16rne_s(vv[r]);
                    ph[r] = (unsigned short)hb;
                    pl[r] = (unsigned short)bf16rne_s(vv[r] - bf16tof(hb));
                }
                *reinterpret_cast<ushort4*>(
                    &Ah[(size_t)(buf * 128 + row) * 40 + col]) = uh;
                *reinterpret_cast<ushort4*>(
                    &Al[(size_t)(buf * 128 + row) * 40 + col]) = ul;
            }
#pragma unroll
            for (int it = 0; it < 2; ++it) {
                const int e = (tid + it * 256) * 4;
                const int krow = e / 64, ncol = e % 64;
                Bh[(buf * 64 + ncol + 0) * 40 + krow] =
                    (unsigned short)bf16rne_s(pb[it].x);
                Bh[(buf * 64 + ncol + 1) * 40 + krow] =
                    (unsigned short)bf16rne_s(pb[it].y);
                Bh[(buf * 64 + ncol + 2) * 40 + krow] =
                    (unsigned short)bf16rne_s(pb[it].z);
                Bh[(buf * 64 + ncol + 3) * 40 + krow] =
                    (unsigned short)bf16rne_s(pb[it].w);
            }
        };

        f32x4 acc[2][4];
#pragma unroll
        for (int i = 0; i < 2; ++i)
#pragma unroll
            for (int j = 0; j < 4; ++j) acc[i][j] = {0.f, 0.f, 0.f, 0.f};

        load_tiles(0);
        commit(0);
        load_tiles(32);
        __syncthreads();

        int cur = 0;
        for (int k0 = 0; k0 < kD; k0 += 32) {
            const bool has_next = (k0 + 32 < kD);
            if (has_next) {
                commit(cur ^ 1);
                if (k0 + 64 < kD) load_tiles(k0 + 64);
            }
            s16x8 ahf[2], alf[2], bhf[4];
#pragma unroll
            for (int i = 0; i < 2; ++i) {
                ahf[i] = *reinterpret_cast<const s16x8*>(
                    &Ah[(size_t)(cur * 128 + wave * 32 + i * 16 + jq) * 40 + hi * 8]);
                alf[i] = *reinterpret_cast<const s16x8*>(
                    &Al[(size_t)(cur * 128 + wave * 32 + i * 16 + jq) * 40 + hi * 8]);
            }
#pragma unroll
            for (int j = 0; j < 4; ++j)
                bhf[j] = *reinterpret_cast<const s16x8*>(
                    &Bh[(size_t)(cur * 64 + j * 16 + jq) * 40 + hi * 8]);
#pragma unroll
            for (int i = 0; i < 2; ++i)
#pragma unroll
                for (int j = 0; j < 4; ++j) {
                    f32x4 c = acc[i][j];
                    c = __builtin_amdgcn_mfma_f32_16x16x32_bf16(ahf[i], bhf[j], c, 0, 0, 0);
                    c = __builtin_amdgcn_mfma_f32_16x16x32_bf16(alf[i], bhf[j], c, 0, 0, 0);
                    acc[i][j] = c;
                }
            if (has_next) __syncthreads();
            cur ^= 1;
        }

#pragma unroll
        for (int i = 0; i < 2; ++i) {
            const int mbase = m0 + wave * 32 + i * 16 + hi * 4;
#pragma unroll
            for (int j = 0; j < 4; ++j) {
                const int n = n0 + j * 16 + jq;
                const float bv = bias[n];
#pragma unroll
                for (int r = 0; r < 4; ++r)
                    C[(size_t)(mbase + r) * k3D + n] = acc[i][j][r] + bv;
            }
        }
    }
}

// ---------------------------------------------------------------------------
// bf16-split MFMA GEMM with bias — output projection (unchanged from r10).
// ---------------------------------------------------------------------------
__global__ __launch_bounds__(256)
void gemm_mfma_kernel(const float* __restrict__ A, const float* __restrict__ Bm,
                      const float* __restrict__ bias, float* __restrict__ C,
                      int M, int K, int ldb, int ldc)
{
    using f32x4 = __attribute__((ext_vector_type(4))) float;
    using s16x8 = __attribute__((ext_vector_type(8))) short;
    constexpr int BM = 128, BN = 64, BK = 32;
    constexpr int AST = 40;

    __shared__ unsigned short Ah[2][BM][AST];
    __shared__ unsigned short Al[2][BM][AST];
    __shared__ unsigned short Bh[2][BN][AST];

    const int tid = threadIdx.x;
    const int wave = tid >> 6, lane = tid & 63;
    const int jq = lane & 15, hi = lane >> 4;
    const int m0 = blockIdx.y * BM, n0 = blockIdx.x * BN;

    float4 pa[4], pb[2];
    auto load_tiles = [&](int k0) {
#pragma unroll
        for (int it = 0; it < 4; ++it) {
            const int e = (tid + it * 256) * 4;
            const int row = e / BK, col = e % BK;
            pa[it] = *reinterpret_cast<const float4*>(
                &A[(size_t)(m0 + row) * K + (k0 + col)]);
        }
#pragma unroll
        for (int it = 0; it < 2; ++it) {
            const int e = (tid + it * 256) * 4;
            const int krow = e / BN, ncol = e % BN;
            pb[it] = *reinterpret_cast<const float4*>(
                &Bm[(size_t)(k0 + krow) * ldb + (n0 + ncol)]);
        }
    };
    auto commit = [&](int buf) {
#pragma unroll
        for (int it = 0; it < 4; ++it) {
            const int e = (tid + it * 256) * 4;
            const int row = e / BK, col = e % BK;
            const float v[4] = {pa[it].x, pa[it].y, pa[it].z, pa[it].w};
            ushort4 uh, ul;
            unsigned short* ph = &uh.x;
            unsigned short* pl = &ul.x;
#pragma unroll
            for (int r = 0; r < 4; ++r) {
                const short hb = bf16rne_s(v[r]);
                ph[r] = (unsigned short)hb;
                pl[r] = (unsigned short)bf16rne_s(v[r] - bf16tof(hb));
            }
            *reinterpret_cast<ushort4*>(&Ah[buf][row][col]) = uh;
            *reinterpret_cast<ushort4*>(&Al[buf][row][col]) = ul;
        }
#pragma unroll
        for (int it = 0; it < 2; ++it) {
            const int e = (tid + it * 256) * 4;
            const int krow = e / BN, ncol = e % BN;
            Bh[buf][ncol + 0][krow] = (unsigned short)bf16rne_s(pb[it].x);
            Bh[buf][ncol + 1][krow] = (unsigned short)bf16rne_s(pb[it].y);
            Bh[buf][ncol + 2][krow] = (unsigned short)bf16rne_s(pb[it].z);
            Bh[buf][ncol + 3][krow] = (unsigned short)bf16rne_s(pb[it].w);
        }
    };

    f32x4 acc[2][4];
#pragma unroll
    for (int i = 0; i < 2; ++i)
#pragma unroll
        for (int j = 0; j < 4; ++j) acc[i][j] = {0.f, 0.f, 0.f, 0.f};

    load_tiles(0);
    commit(0);
    load_tiles(BK);
    __syncthreads();

    int cur = 0;
    for (int k0 = 0; k0 < K; k0 += BK) {
        const bool has_next = (k0 + BK < K);
        if (has_next) {
            commit(cur ^ 1);
            if (k0 + 2 * BK < K) load_tiles(k0 + 2 * BK);
        }
        s16x8 ahf[2], alf[2], bhf[4];
#pragma unroll
        for (int i = 0; i < 2; ++i) {
            ahf[i] = *reinterpret_cast<const s16x8*>(
                &Ah[cur][wave * 32 + i * 16 + jq][hi * 8]);
            alf[i] = *reinterpret_cast<const s16x8*>(
                &Al[cur][wave * 32 + i * 16 + jq][hi * 8]);
        }
#pragma unroll
        for (int j = 0; j < 4; ++j)
            bhf[j] = *reinterpret_cast<const s16x8*>(
                &Bh[cur][j * 16 + jq][hi * 8]);
#pragma unroll
        for (int i = 0; i < 2; ++i)
#pragma unroll
            for (int j = 0; j < 4; ++j) {
                f32x4 c = acc[i][j];
                c = __builtin_amdgcn_mfma_f32_16x16x32_bf16(ahf[i], bhf[j], c, 0, 0, 0);
                c = __builtin_amdgcn_mfma_f32_16x16x32_bf16(alf[i], bhf[j], c, 0, 0, 0);
                acc[i][j] = c;
            }
        if (has_next) __syncthreads();
        cur ^= 1;
    }

#pragma unroll
    for (int i = 0; i < 2; ++i) {
        const int mbase = m0 + wave * 32 + i * 16 + hi * 4;
#pragma unroll
        for (int j = 0; j < 4; ++j) {
            const int n = n0 + j * 16 + jq;
            const float bv = bias[n];
#pragma unroll
            for (int r = 0; r < 4; ++r)
                C[(size_t)(mbase + r) * ldc + n] = acc[i][j][r] + bv;
        }
    }
}

// ---------------------------------------------------------------------------
// Per-key V suffix sums: vsuf[b][h][k][d] = sum_{j>=k} V[b][j][h*64+d].
// ---------------------------------------------------------------------------
__global__ __launch_bounds__(256)
void vsuf_kernel(const float* __restrict__ qkv, float* __restrict__ vsuf)
{
    const int h = blockIdx.x, b = blockIdx.y;
    const int lane = threadIdx.x & 63, wave = threadIdx.x >> 6;
    const float* vp = qkv + (size_t)b * kS * k3D + 2 * kD + h * kHD;
    float* op = vsuf + (size_t)(b * kH + h) * kS * kHD;
    __shared__ float csum[4][64];

    const int kBeg = wave * 512, kEnd = kBeg + 512;
    float s = 0.0f;
#pragma unroll 8
    for (int k = kBeg; k < kEnd; ++k)
        s += vp[(size_t)k * k3D + lane];
    csum[wave][lane] = s;
    __syncthreads();

    float run = 0.0f;
    for (int w = wave + 1; w < 4; ++w) run += csum[w][lane];
#pragma unroll 8
    for (int k = kEnd - 1; k >= kBeg; --k) {
        run += vp[(size_t)k * k3D + lane];
        op[(size_t)k * kHD + lane] = run;
    }
}

// ---------------------------------------------------------------------------
// Attention: SINGLE-PASS bf16-MFMA scan with per-lane running-max rescue.
// Rescue condition: raw approx score >= lane_running_max - delta. Since
// lane_running_max <= global_approx_max <= exact_max + eps and any exact-max
// key's approx score >= exact_max - eps, delta=0.25 > 2*eps guarantees the
// rescued set is a SUPERSET of the two-pass set => exact bookkeeping result
// identical to rounds 1-10 (selection bit-exact). All comparisons in raw-dot
// space (mask_affine monotone), so no 1e9 error amplification.
// ---------------------------------------------------------------------------
__global__ __launch_bounds__(256, 4)
void attn_mfma_kernel(const float* __restrict__ qkv,
                      const float* __restrict__ vsuf,
                      float* __restrict__ ctx)
{
    using f32x4 = __attribute__((ext_vector_type(4))) float;
    using s16x8 = __attribute__((ext_vector_type(8))) short;

    const int id = blockIdx.x;
    const int bh = id % (kB * kH);
    const int t  = id / (kB * kH);
    const int b = bh / kH, h = bh % kH;

    const int tid = threadIdx.x;
    const int wave = tid >> 6, lane = tid & 63;
    const int jq = lane & 15, hi = lane >> 4;
    const int qrow = wave * 16 + jq;
    const int qglob = t * 64 + qrow;

    __shared__ float Qf[64][68];
    __shared__ float Kf[64][68];
    __shared__ float MgS[64];
    __shared__ int   CgS[64], I0S[64], I1S[64];

    const float* qp = qkv + (size_t)b * kS * k3D + h * kHD;
    const float* kp = qp + kD;
    const float* vp = qp + 2 * kD;

    // stage Q tile, prescaled by 0.125 (exact power of two, same as r1)
#pragma unroll
    for (int i = 0; i < 4; ++i) {
        const int f4 = tid + i * 256;
        const int r = f4 >> 4, d4 = f4 & 15;
        float4 v = *reinterpret_cast<const float4*>(
            &qp[(size_t)(t * 64 + r) * k3D + d4 * 4]);
        v.x *= 0.125f; v.y *= 0.125f; v.z *= 0.125f; v.w *= 0.125f;
        *reinterpret_cast<float4*>(&Qf[r][d4 * 4]) = v;
    }
    __syncthreads();

    auto mkfrag = [&](const float* p) {
        const float4 a = *reinterpret_cast<const float4*>(p);
        const float4 c = *reinterpret_cast<const float4*>(p + 4);
        s16x8 r;
        r[0] = bf16rne_s(a.x); r[1] = bf16rne_s(a.y);
        r[2] = bf16rne_s(a.z); r[3] = bf16rne_s(a.w);
        r[4] = bf16rne_s(c.x); r[5] = bf16rne_s(c.y);
        r[6] = bf16rne_s(c.z); r[7] = bf16rne_s(c.w);
        return r;
    };

    const s16x8 bq0 = mkfrag(&Qf[qrow][hi * 8]);
    const s16x8 bq1 = mkfrag(&Qf[qrow][32 + hi * 8]);

    auto stage_k = [&](int kt) {
#pragma unroll
        for (int i = 0; i < 4; ++i) {
            const int f4 = tid + i * 256;
            const int r = f4 >> 4, d4 = f4 & 15;
            *reinterpret_cast<float4*>(&Kf[r][d4 * 4]) =
                *reinterpret_cast<const float4*>(
                    &kp[(size_t)(kt * 64 + r) * k3D + d4 * 4]);
        }
    };

    // single pass: approx scores + per-lane running max + inline exact rescue
    float mrun = -INFINITY;          // raw approx running max (lane's keys)
    float m = -INFINITY;             // exact masked-score max
    int cnt = 0, i0 = -1, i1 = -1;

    for (int kt = 0; kt <= t; ++kt) {
        __syncthreads();
        stage_k(kt);
        __syncthreads();
#pragma unroll
        for (int g = 0; g < 4; ++g) {
            const s16x8 a0 = mkfrag(&Kf[g * 16 + jq][hi * 8]);
            const s16x8 a1 = mkfrag(&Kf[g * 16 + jq][32 + hi * 8]);
            f32x4 c = {0.f, 0.f, 0.f, 0.f};
            c = __builtin_amdgcn_mfma_f32_16x16x32_bf16(a0, bq0, c, 0, 0, 0);
            c = __builtin_amdgcn_mfma_f32_16x16x32_bf16(a1, bq1, c, 0, 0, 0);
#pragma unroll
            for (int r = 0; r < 4; ++r) {
                const int key = kt * 64 + g * 16 + hi * 4 + r;
                if (key <= qglob) {
                    const float sa = c[r];
                    if (sa >= mrun - kDelta) {
                        // exact rescue: frozen r1 chain from fp32 LDS tiles
                        const float* qr = &Qf[qrow][0];
                        const float* kr = &Kf[key - kt * 64][0];
                        float dot = 0.0f;
#pragma unroll
                        for (int d4 = 0; d4 < 16; ++d4) {
                            const float4 q4 = *reinterpret_cast<const float4*>(qr + d4 * 4);
                            const float4 k4 = *reinterpret_cast<const float4*>(kr + d4 * 4);
                            dot = fmaf(q4.x, k4.x, dot);
                            dot = fmaf(q4.y, k4.y, dot);
                            dot = fmaf(q4.z, k4.z, dot);
                            dot = fmaf(q4.w, k4.w, dot);
                        }
                        const float s = mask_affine(dot);
                        const bool upd = (s > m), tie = (s == m);
                        i1 = upd ? -1 : ((tie && cnt == 1) ? key : i1);
                        i0 = upd ? key : i0;
                        cnt = upd ? 1 : (tie ? cnt + 1 : cnt);
                        m = upd ? s : m;
                    }
                    mrun = fmaxf(mrun, sa);
                }
            }
        }
    }

    // merge the 4 lanes sharing each query column
#pragma unroll
    for (int off = 16; off <= 32; off <<= 1) {
        const float mo = __shfl_xor(m, off);
        const int co = __shfl_xor(cnt, off);
        const int o0 = __shfl_xor(i0, off);
        const int o1 = __shfl_xor(i1, off);
        if (mo > m) { m = mo; cnt = co; i0 = o0; i1 = o1; }
        else if (mo == m && co > 0) {
            if (cnt == 0) { i0 = o0; i1 = o1; }
            else if (cnt == 1) { i1 = o0; }
            cnt += co;
        }
    }
    if (hi == 0) {
        MgS[wave * 16 + jq] = m; CgS[wave * 16 + jq] = cnt;
        I0S[wave * 16 + jq] = i0; I1S[wave * 16 + jq] = i1;
    }
    __syncthreads();

    // ---- epilogue: 4 threads per query, 16 dims each ----
    const int qloc = tid >> 2, qtr = tid & 3;
    const int qi = t * 64 + qloc;
    float mg = MgS[qloc];
    int fcnt = CgS[qloc], f0 = I0S[qloc], f1 = I1S[qloc];

    bool addsuf = false;
    if (qi < kS - 1) {
        const bool lt = (mg < kNeg), eq = (mg == kNeg);
        if (lt)      { fcnt = kS - 1 - qi; f0 = -1; f1 = -1; addsuf = true; }
        else if (eq) { fcnt += kS - 1 - qi; addsuf = true; }
    }

    float4 a4[4];
#pragma unroll
    for (int i = 0; i < 4; ++i) a4[i] = {0.f, 0.f, 0.f, 0.f};

    if (f0 >= 0) {
        const float* vr = vp + (size_t)f0 * k3D + qtr * 16;
#pragma unroll
        for (int i = 0; i < 4; ++i) {
            const float4 v = *reinterpret_cast<const float4*>(vr + i * 4);
            a4[i].x += v.x; a4[i].y += v.y; a4[i].z += v.z; a4[i].w += v.w;
        }
    }
    if (f1 >= 0) {
        const float* vr = vp + (size_t)f1 * k3D + qtr * 16;
#pragma unroll
        for (int i = 0; i < 4; ++i) {
            const float4 v = *reinterpret_cast<const float4*>(vr + i * 4);
            a4[i].x += v.x; a4[i].y += v.y; a4[i].z += v.z; a4[i].w += v.w;
        }
    }
    if (addsuf) {
        const float* sp = vsuf + ((size_t)(b * kH + h) * kS + (qi + 1)) * kHD
                          + qtr * 16;
#pragma unroll
        for (int i = 0; i < 4; ++i) {
            const float4 v = *reinterpret_cast<const float4*>(sp + i * 4);
            a4[i].x += v.x; a4[i].y += v.y; a4[i].z += v.z; a4[i].w += v.w;
        }
    }

    float* op = ctx + ((size_t)b * kS + qi) * kD + h * kHD + qtr * 16;
    const float fc = (float)fcnt;
#pragma unroll
    for (int i = 0; i < 4; ++i) {
        const float4 r = {a4[i].x / fc, a4[i].y / fc, a4[i].z / fc, a4[i].w / fc};
        *reinterpret_cast<float4*>(op + i * 4) = r;
    }
}

// ---------------------------------------------------------------------------
extern "C" void kernel_launch(void* const* d_in, const int* in_sizes, int n_in,
                              void* d_out, int out_size, void* d_ws, size_t ws_size,
                              hipStream_t stream)
{
    const float* x     = (const float*)d_in[0];
    const float* W_qkv = (const float*)d_in[1];
    const float* b_qkv = (const float*)d_in[2];
    const float* W_o   = (const float*)d_in[3];
    const float* b_o   = (const float*)d_in[4];
    float* out = (float*)d_out;

    // workspace: qkv [8192][2304] (75.5 MB) + ctx [8192][768] (25 MB).
    // vsuf (25.2 MB) lives in d_out, fully overwritten by the final GEMM.
    float* qkv  = (float*)d_ws;
    float* ctx  = qkv + (size_t)kB * kS * k3D;
    float* vsuf = out;

    // 1) FUSED projection: even blocks = exact fp32 QK GEMM (bit-frozen),
    //    odd blocks = staged-split bf16 MFMA V GEMM. Pipes overlap.
    {
        fused_proj_kernel<<<dim3(1536), 256, 0, stream>>>(x, W_qkv, b_qkv, qkv);
    }
    // 2) per-key V suffix sums (for the all-masked-dominated rows)
    {
        dim3 grid(kH, kB);
        vsuf_kernel<<<grid, 256, 0, stream>>>(qkv, vsuf);
    }
    // 3) attention: single-pass MFMA scan + inline exact fp32 rescue
    //    (selection identical to rounds 1-10)
    {
        attn_mfma_kernel<<<dim3((kS / 64) * kB * kH), 256, 0, stream>>>(
            qkv, vsuf, ctx);
    }
    // 4) out = ctx @ W_o + b_o : staged-split bf16 MFMA GEMM
    {
        dim3 grid(kD / 64, (kB * kS) / 128);
        gemm_mfma_kernel<<<grid, 256, 0, stream>>>(
            ctx, W_o, b_o, out, kB * kS, kD, kD, kD);
    }
}

// Round 12
// 730.620 us; speedup vs baseline: 1.4404x; 1.4404x over previous
//
#include <hip/hip_runtime.h>
#include <cmath>
#include <cstdint>
#include <cstddef>

namespace {
constexpr int kB = 4;
constexpr int kS = 2048;
constexpr int kD = 768;
constexpr int kH = 12;
constexpr int kHD = 64;
constexpr int k3D = 3 * kD;   // 2304
constexpr float kNeg = -1000000000.0f;
constexpr float kDelta = 0.25f;   // rescue margin >= 2 * bf16 dot error bound
}

// Faithful fp32 masking affine: s = a + NEG*(1-a), no fma contraction so the
// rounding sequence matches numpy's elementwise ops. (Identical to rounds 1-11.)
__device__ __forceinline__ float mask_affine(float a) {
#pragma clang fp contract(off)
    const float u = 1.0f - a;
    return a + kNeg * u;
}

__device__ __forceinline__ short bf16rne_s(float f) {
    uint32_t u = __builtin_bit_cast(uint32_t, f);
    u += 0x7FFFu + ((u >> 16) & 1u);
    return (short)(u >> 16);
}
__device__ __forceinline__ float bf16tof(short h) {
    const uint32_t u = ((uint32_t)(unsigned short)h) << 16;
    return __builtin_bit_cast(float, u);
}

// ---------------------------------------------------------------------------
// EXACT fp32 tiled GEMM with bias (Q,K columns — selection-critical).
// Round-7/10 measured-good geometry: 256 threads, 8x8 microtile, BK=16, dbuf,
// one barrier per K-tile. Frozen k-ascending fmaf chain per output.
// ---------------------------------------------------------------------------
template <int BM, int BN, int BK, int TM, int TN>
__global__ __launch_bounds__(BM * BN / (TM * TN))
void gemm_bias_kernel(const float* __restrict__ A, const float* __restrict__ Bm,
                      const float* __restrict__ bias, float* __restrict__ C,
                      int M, int K, int ldb, int ldc)
{
    constexpr int THREADS = BM * BN / (TM * TN);
    constexpr int TX = BN / TN;
    constexpr int TY = THREADS / TX;
    static_assert(TX == 16 && TY * TM == BM, "geometry");
    constexpr int AF4 = BM * BK / (THREADS * 4);
    constexpr int BF4 = BK * BN / (THREADS * 4);
    constexpr int BSTR = BK * TN + 4;

    __shared__ float As[2][BK][BM + 4];
    __shared__ float Bs[2][TX][BSTR];

    const int tid = threadIdx.x;
    const int tx = tid % TX, ty = tid / TX;
    const int m0 = blockIdx.y * BM, n0 = blockIdx.x * BN;

    float4 pa[AF4], pb[BF4];
    auto load_tiles = [&](int k0) {
#pragma unroll
        for (int it = 0; it < AF4; ++it) {
            const int e = (tid + it * THREADS) * 4;
            const int row = e / BK, col = e % BK;
            pa[it] = *reinterpret_cast<const float4*>(
                &A[(size_t)(m0 + row) * K + (k0 + col)]);
        }
#pragma unroll
        for (int it = 0; it < BF4; ++it) {
            const int e = (tid + it * THREADS) * 4;
            const int row = e / BN, col = e % BN;
            pb[it] = *reinterpret_cast<const float4*>(
                &Bm[(size_t)(k0 + row) * ldb + (n0 + col)]);
        }
    };
    auto commit = [&](int buf) {
#pragma unroll
        for (int it = 0; it < AF4; ++it) {
            const int e = (tid + it * THREADS) * 4;
            const int row = e / BK, col = e % BK;
            As[buf][col + 0][row] = pa[it].x;
            As[buf][col + 1][row] = pa[it].y;
            As[buf][col + 2][row] = pa[it].z;
            As[buf][col + 3][row] = pa[it].w;
        }
#pragma unroll
        for (int it = 0; it < BF4; ++it) {
            const int e = (tid + it * THREADS) * 4;
            const int row = e / BN, col = e % BN;
            const int g = col / TN, off = col % TN;
            *reinterpret_cast<float4*>(&Bs[buf][g][row * TN + off]) = pb[it];
        }
    };

    float acc[TM][TN];
#pragma unroll
    for (int i = 0; i < TM; ++i)
#pragma unroll
        for (int j = 0; j < TN; ++j) acc[i][j] = 0.0f;

    load_tiles(0);
    commit(0);
    load_tiles(BK);
    __syncthreads();

    int cur = 0;
    for (int k0 = 0; k0 < K; k0 += BK) {
        const bool has_next = (k0 + BK < K);
        if (has_next) {
            commit(cur ^ 1);
            if (k0 + 2 * BK < K) load_tiles(k0 + 2 * BK);
        }
#pragma unroll
        for (int kk = 0; kk < BK; ++kk) {
            float a[TM], b[TN];
#pragma unroll
            for (int i = 0; i < TM; i += 4) {
                const float4 v = *reinterpret_cast<const float4*>(
                    &As[cur][kk][ty * TM + i]);
                a[i] = v.x; a[i + 1] = v.y; a[i + 2] = v.z; a[i + 3] = v.w;
            }
#pragma unroll
            for (int j = 0; j < TN; j += 4) {
                const float4 v = *reinterpret_cast<const float4*>(
                    &Bs[cur][tx][kk * TN + j]);
                b[j] = v.x; b[j + 1] = v.y; b[j + 2] = v.z; b[j + 3] = v.w;
            }
#pragma unroll
            for (int i = 0; i < TM; ++i)
#pragma unroll
                for (int j = 0; j < TN; ++j)
                    acc[i][j] = fmaf(a[i], b[j], acc[i][j]);
        }
        if (has_next) __syncthreads();
        cur ^= 1;
    }

#pragma unroll
    for (int i = 0; i < TM; ++i) {
        const int m = m0 + ty * TM + i;
#pragma unroll
        for (int j = 0; j < TN; ++j) {
            const int n = n0 + tx * TN + j;
            C[(size_t)m * ldc + n] = acc[i][j] + bias[n];
        }
    }
}

// ---------------------------------------------------------------------------
// bf16-split MFMA GEMM with bias (V projection + output projection — NOT
// selection-critical). Unchanged from round 10.
// ---------------------------------------------------------------------------
__global__ __launch_bounds__(256)
void gemm_mfma_kernel(const float* __restrict__ A, const float* __restrict__ Bm,
                      const float* __restrict__ bias, float* __restrict__ C,
                      int M, int K, int ldb, int ldc)
{
    using f32x4 = __attribute__((ext_vector_type(4))) float;
    using s16x8 = __attribute__((ext_vector_type(8))) short;
    constexpr int BM = 128, BN = 64, BK = 32;
    constexpr int AST = 40;

    __shared__ unsigned short Ah[2][BM][AST];
    __shared__ unsigned short Al[2][BM][AST];
    __shared__ unsigned short Bh[2][BN][AST];

    const int tid = threadIdx.x;
    const int wave = tid >> 6, lane = tid & 63;
    const int jq = lane & 15, hi = lane >> 4;
    const int m0 = blockIdx.y * BM, n0 = blockIdx.x * BN;

    float4 pa[4], pb[2];
    auto load_tiles = [&](int k0) {
#pragma unroll
        for (int it = 0; it < 4; ++it) {
            const int e = (tid + it * 256) * 4;
            const int row = e / BK, col = e % BK;
            pa[it] = *reinterpret_cast<const float4*>(
                &A[(size_t)(m0 + row) * K + (k0 + col)]);
        }
#pragma unroll
        for (int it = 0; it < 2; ++it) {
            const int e = (tid + it * 256) * 4;
            const int krow = e / BN, ncol = e % BN;
            pb[it] = *reinterpret_cast<const float4*>(
                &Bm[(size_t)(k0 + krow) * ldb + (n0 + ncol)]);
        }
    };
    auto commit = [&](int buf) {
#pragma unroll
        for (int it = 0; it < 4; ++it) {
            const int e = (tid + it * 256) * 4;
            const int row = e / BK, col = e % BK;
            const float v[4] = {pa[it].x, pa[it].y, pa[it].z, pa[it].w};
            ushort4 uh, ul;
            unsigned short* ph = &uh.x;
            unsigned short* pl = &ul.x;
#pragma unroll
            for (int r = 0; r < 4; ++r) {
                const short hb = bf16rne_s(v[r]);
                ph[r] = (unsigned short)hb;
                pl[r] = (unsigned short)bf16rne_s(v[r] - bf16tof(hb));
            }
            *reinterpret_cast<ushort4*>(&Ah[buf][row][col]) = uh;
            *reinterpret_cast<ushort4*>(&Al[buf][row][col]) = ul;
        }
#pragma unroll
        for (int it = 0; it < 2; ++it) {
            const int e = (tid + it * 256) * 4;
            const int krow = e / BN, ncol = e % BN;
            Bh[buf][ncol + 0][krow] = (unsigned short)bf16rne_s(pb[it].x);
            Bh[buf][ncol + 1][krow] = (unsigned short)bf16rne_s(pb[it].y);
            Bh[buf][ncol + 2][krow] = (unsigned short)bf16rne_s(pb[it].z);
            Bh[buf][ncol + 3][krow] = (unsigned short)bf16rne_s(pb[it].w);
        }
    };

    f32x4 acc[2][4];
#pragma unroll
    for (int i = 0; i < 2; ++i)
#pragma unroll
        for (int j = 0; j < 4; ++j) acc[i][j] = {0.f, 0.f, 0.f, 0.f};

    load_tiles(0);
    commit(0);
    load_tiles(BK);
    __syncthreads();

    int cur = 0;
    for (int k0 = 0; k0 < K; k0 += BK) {
        const bool has_next = (k0 + BK < K);
        if (has_next) {
            commit(cur ^ 1);
            if (k0 + 2 * BK < K) load_tiles(k0 + 2 * BK);
        }
        s16x8 ahf[2], alf[2], bhf[4];
#pragma unroll
        for (int i = 0; i < 2; ++i) {
            ahf[i] = *reinterpret_cast<const s16x8*>(
                &Ah[cur][wave * 32 + i * 16 + jq][hi * 8]);
            alf[i] = *reinterpret_cast<const s16x8*>(
                &Al[cur][wave * 32 + i * 16 + jq][hi * 8]);
        }
#pragma unroll
        for (int j = 0; j < 4; ++j)
            bhf[j] = *reinterpret_cast<const s16x8*>(
                &Bh[cur][j * 16 + jq][hi * 8]);
#pragma unroll
        for (int i = 0; i < 2; ++i)
#pragma unroll
            for (int j = 0; j < 4; ++j) {
                f32x4 c = acc[i][j];
                c = __builtin_amdgcn_mfma_f32_16x16x32_bf16(ahf[i], bhf[j], c, 0, 0, 0);
                c = __builtin_amdgcn_mfma_f32_16x16x32_bf16(alf[i], bhf[j], c, 0, 0, 0);
                acc[i][j] = c;
            }
        if (has_next) __syncthreads();
        cur ^= 1;
    }

#pragma unroll
    for (int i = 0; i < 2; ++i) {
        const int mbase = m0 + wave * 32 + i * 16 + hi * 4;
#pragma unroll
        for (int j = 0; j < 4; ++j) {
            const int n = n0 + j * 16 + jq;
            const float bv = bias[n];
#pragma unroll
            for (int r = 0; r < 4; ++r)
                C[(size_t)(mbase + r) * ldc + n] = acc[i][j][r] + bv;
        }
    }
}

// ---------------------------------------------------------------------------
// Per-key V suffix sums: vsuf[b][h][k][d] = sum_{j>=k} V[b][j][h*64+d].
// ---------------------------------------------------------------------------
__global__ __launch_bounds__(256)
void vsuf_kernel(const float* __restrict__ qkv, float* __restrict__ vsuf)
{
    const int h = blockIdx.x, b = blockIdx.y;
    const int lane = threadIdx.x & 63, wave = threadIdx.x >> 6;
    const float* vp = qkv + (size_t)b * kS * k3D + 2 * kD + h * kHD;
    float* op = vsuf + (size_t)(b * kH + h) * kS * kHD;
    __shared__ float csum[4][64];

    const int kBeg = wave * 512, kEnd = kBeg + 512;
    float s = 0.0f;
#pragma unroll 8
    for (int k = kBeg; k < kEnd; ++k)
        s += vp[(size_t)k * k3D + lane];
    csum[wave][lane] = s;
    __syncthreads();

    float run = 0.0f;
    for (int w = wave + 1; w < 4; ++w) run += csum[w][lane];
#pragma unroll 8
    for (int k = kEnd - 1; k >= kBeg; --k) {
        run += vp[(size_t)k * k3D + lane];
        op[(size_t)k * kHD + lane] = run;
    }
}

// ---------------------------------------------------------------------------
// Attention: SINGLE-PASS bf16-MFMA scan, TILE-DEFERRED rescue threshold.
// Per tile: compute all 16 approx scores, fold the tile max into mrun FIRST,
// then rescue keys with sa >= mrun - delta using the frozen fp32 chain from
// the LDS tiles. Superset proof: mrun_tile <= lane's global approx max <=
// raw(k*) + 2*eps, delta = 0.25 > 2*eps => every exact-max/tie key rescued;
// non-rescued keys are strictly below the exact max => final (m,cnt,i0,i1)
// identical to the r10 two-pass version (selection bit-exact, rounds 1-10).
// Tile-deferral kills r11's early-scan rescue storm (first tile rescues only
// keys within delta of the FIRST tile's max).
// ---------------------------------------------------------------------------
__global__ __launch_bounds__(256, 4)
void attn_mfma_kernel(const float* __restrict__ qkv,
                      const float* __restrict__ vsuf,
                      float* __restrict__ ctx)
{
    using f32x4 = __attribute__((ext_vector_type(4))) float;
    using s16x8 = __attribute__((ext_vector_type(8))) short;

    const int id = blockIdx.x;
    const int bh = id % (kB * kH);
    const int t  = id / (kB * kH);
    const int b = bh / kH, h = bh % kH;

    const int tid = threadIdx.x;
    const int wave = tid >> 6, lane = tid & 63;
    const int jq = lane & 15, hi = lane >> 4;
    const int qrow = wave * 16 + jq;
    const int qglob = t * 64 + qrow;

    __shared__ float Qf[64][68];
    __shared__ float Kf[64][68];
    __shared__ float MgS[64];
    __shared__ int   CgS[64], I0S[64], I1S[64];

    const float* qp = qkv + (size_t)b * kS * k3D + h * kHD;
    const float* kp = qp + kD;
    const float* vp = qp + 2 * kD;

    // stage Q tile, prescaled by 0.125 (exact power of two, same as r1)
#pragma unroll
    for (int i = 0; i < 4; ++i) {
        const int f4 = tid + i * 256;
        const int r = f4 >> 4, d4 = f4 & 15;
        float4 v = *reinterpret_cast<const float4*>(
            &qp[(size_t)(t * 64 + r) * k3D + d4 * 4]);
        v.x *= 0.125f; v.y *= 0.125f; v.z *= 0.125f; v.w *= 0.125f;
        *reinterpret_cast<float4*>(&Qf[r][d4 * 4]) = v;
    }
    __syncthreads();

    auto mkfrag = [&](const float* p) {
        const float4 a = *reinterpret_cast<const float4*>(p);
        const float4 c = *reinterpret_cast<const float4*>(p + 4);
        s16x8 r;
        r[0] = bf16rne_s(a.x); r[1] = bf16rne_s(a.y);
        r[2] = bf16rne_s(a.z); r[3] = bf16rne_s(a.w);
        r[4] = bf16rne_s(c.x); r[5] = bf16rne_s(c.y);
        r[6] = bf16rne_s(c.z); r[7] = bf16rne_s(c.w);
        return r;
    };

    const s16x8 bq0 = mkfrag(&Qf[qrow][hi * 8]);
    const s16x8 bq1 = mkfrag(&Qf[qrow][32 + hi * 8]);

    auto stage_k = [&](int kt) {
#pragma unroll
        for (int i = 0; i < 4; ++i) {
            const int f4 = tid + i * 256;
            const int r = f4 >> 4, d4 = f4 & 15;
            *reinterpret_cast<float4*>(&Kf[r][d4 * 4]) =
                *reinterpret_cast<const float4*>(
                    &kp[(size_t)(kt * 64 + r) * k3D + d4 * 4]);
        }
    };

    float mrun = -INFINITY;          // running approx max over lane's VALID keys
    float m = -INFINITY;             // exact masked-score max
    int cnt = 0, i0 = -1, i1 = -1;

    for (int kt = 0; kt <= t; ++kt) {
        __syncthreads();
        stage_k(kt);
        __syncthreads();

        f32x4 acc[4];
#pragma unroll
        for (int g = 0; g < 4; ++g) {
            const s16x8 a0 = mkfrag(&Kf[g * 16 + jq][hi * 8]);
            const s16x8 a1 = mkfrag(&Kf[g * 16 + jq][32 + hi * 8]);
            f32x4 c = {0.f, 0.f, 0.f, 0.f};
            c = __builtin_amdgcn_mfma_f32_16x16x32_bf16(a0, bq0, c, 0, 0, 0);
            c = __builtin_amdgcn_mfma_f32_16x16x32_bf16(a1, bq1, c, 0, 0, 0);
            acc[g] = c;
        }

        // fold tile max into mrun FIRST (valid keys only)
#pragma unroll
        for (int g = 0; g < 4; ++g)
#pragma unroll
            for (int r = 0; r < 4; ++r) {
                const int key = kt * 64 + g * 16 + hi * 4 + r;
                if (key <= qglob) mrun = fmaxf(mrun, acc[g][r]);
            }
        const float thr = mrun - kDelta;

        // rescue candidates (ascending key order, frozen fp32 chain from LDS)
#pragma unroll
        for (int g = 0; g < 4; ++g)
#pragma unroll
            for (int r = 0; r < 4; ++r) {
                const int key = kt * 64 + g * 16 + hi * 4 + r;
                if (key <= qglob && acc[g][r] >= thr) {
                    const float* qr = &Qf[qrow][0];
                    const float* kr = &Kf[key - kt * 64][0];
                    float dot = 0.0f;
#pragma unroll
                    for (int d4 = 0; d4 < 16; ++d4) {
                        const float4 q4 = *reinterpret_cast<const float4*>(qr + d4 * 4);
                        const float4 k4 = *reinterpret_cast<const float4*>(kr + d4 * 4);
                        dot = fmaf(q4.x, k4.x, dot);
                        dot = fmaf(q4.y, k4.y, dot);
                        dot = fmaf(q4.z, k4.z, dot);
                        dot = fmaf(q4.w, k4.w, dot);
                    }
                    const float s = mask_affine(dot);
                    const bool upd = (s > m), tie = (s == m);
                    i1 = upd ? -1 : ((tie && cnt == 1) ? key : i1);
                    i0 = upd ? key : i0;
                    cnt = upd ? 1 : (tie ? cnt + 1 : cnt);
                    m = upd ? s : m;
                }
            }
    }

    // merge the 4 lanes sharing each query column
#pragma unroll
    for (int off = 16; off <= 32; off <<= 1) {
        const float mo = __shfl_xor(m, off);
        const int co = __shfl_xor(cnt, off);
        const int o0 = __shfl_xor(i0, off);
        const int o1 = __shfl_xor(i1, off);
        if (mo > m) { m = mo; cnt = co; i0 = o0; i1 = o1; }
        else if (mo == m && co > 0) {
            if (cnt == 0) { i0 = o0; i1 = o1; }
            else if (cnt == 1) { i1 = o0; }
            cnt += co;
        }
    }
    if (hi == 0) {
        MgS[wave * 16 + jq] = m; CgS[wave * 16 + jq] = cnt;
        I0S[wave * 16 + jq] = i0; I1S[wave * 16 + jq] = i1;
    }
    __syncthreads();

    // ---- epilogue: 4 threads per query, 16 dims each ----
    const int qloc = tid >> 2, qtr = tid & 3;
    const int qi = t * 64 + qloc;
    float mg = MgS[qloc];
    int fcnt = CgS[qloc], f0 = I0S[qloc], f1 = I1S[qloc];

    bool addsuf = false;
    if (qi < kS - 1) {
        const bool lt = (mg < kNeg), eq = (mg == kNeg);
        if (lt)      { fcnt = kS - 1 - qi; f0 = -1; f1 = -1; addsuf = true; }
        else if (eq) { fcnt += kS - 1 - qi; addsuf = true; }
    }

    float4 a4[4];
#pragma unroll
    for (int i = 0; i < 4; ++i) a4[i] = {0.f, 0.f, 0.f, 0.f};

    if (f0 >= 0) {
        const float* vr = vp + (size_t)f0 * k3D + qtr * 16;
#pragma unroll
        for (int i = 0; i < 4; ++i) {
            const float4 v = *reinterpret_cast<const float4*>(vr + i * 4);
            a4[i].x += v.x; a4[i].y += v.y; a4[i].z += v.z; a4[i].w += v.w;
        }
    }
    if (f1 >= 0) {
        const float* vr = vp + (size_t)f1 * k3D + qtr * 16;
#pragma unroll
        for (int i = 0; i < 4; ++i) {
            const float4 v = *reinterpret_cast<const float4*>(vr + i * 4);
            a4[i].x += v.x; a4[i].y += v.y; a4[i].z += v.z; a4[i].w += v.w;
        }
    }
    if (addsuf) {
        const float* sp = vsuf + ((size_t)(b * kH + h) * kS + (qi + 1)) * kHD
                          + qtr * 16;
#pragma unroll
        for (int i = 0; i < 4; ++i) {
            const float4 v = *reinterpret_cast<const float4*>(sp + i * 4);
            a4[i].x += v.x; a4[i].y += v.y; a4[i].z += v.z; a4[i].w += v.w;
        }
    }

    float* op = ctx + ((size_t)b * kS + qi) * kD + h * kHD + qtr * 16;
    const float fc = (float)fcnt;
#pragma unroll
    for (int i = 0; i < 4; ++i) {
        const float4 r = {a4[i].x / fc, a4[i].y / fc, a4[i].z / fc, a4[i].w / fc};
        *reinterpret_cast<float4*>(op + i * 4) = r;
    }
}

// ---------------------------------------------------------------------------
extern "C" void kernel_launch(void* const* d_in, const int* in_sizes, int n_in,
                              void* d_out, int out_size, void* d_ws, size_t ws_size,
                              hipStream_t stream)
{
    const float* x     = (const float*)d_in[0];
    const float* W_qkv = (const float*)d_in[1];
    const float* b_qkv = (const float*)d_in[2];
    const float* W_o   = (const float*)d_in[3];
    const float* b_o   = (const float*)d_in[4];
    float* out = (float*)d_out;

    // workspace: qkv [8192][2304] (75.5 MB) + ctx [8192][768] (25 MB).
    // vsuf (25.2 MB) lives in d_out, fully overwritten by the final GEMM.
    float* qkv  = (float*)d_ws;
    float* ctx  = qkv + (size_t)kB * kS * k3D;
    float* vsuf = out;

    // 1a) Q,K columns: EXACT fp32 GEMM (selection-critical, chain frozen)
    {
        dim3 grid(1536 / 128, (kB * kS) / 128);
        gemm_bias_kernel<128, 128, 16, 8, 8><<<grid, 256, 0, stream>>>(
            x, W_qkv, b_qkv, qkv, kB * kS, kD, k3D, k3D);
    }
    // 1b) V columns: staged-split bf16 MFMA GEMM (not selection-critical)
    {
        dim3 grid(kD / 64, (kB * kS) / 128);
        gemm_mfma_kernel<<<grid, 256, 0, stream>>>(
            x, W_qkv + 2 * kD, b_qkv + 2 * kD, qkv + 2 * kD,
            kB * kS, kD, k3D, k3D);
    }
    // 1c) per-key V suffix sums (for the all-masked-dominated rows)
    {
        dim3 grid(kH, kB);
        vsuf_kernel<<<grid, 256, 0, stream>>>(qkv, vsuf);
    }
    // 2) attention: single-pass MFMA scan, tile-deferred exact rescue
    //    (selection identical to rounds 1-10)
    {
        attn_mfma_kernel<<<dim3((kS / 64) * kB * kH), 256, 0, stream>>>(
            qkv, vsuf, ctx);
    }
    // 3) out = ctx @ W_o + b_o : staged-split bf16 MFMA GEMM
    {
        dim3 grid(kD / 64, (kB * kS) / 128);
        gemm_mfma_kernel<<<grid, 256, 0, stream>>>(
            ctx, W_o, b_o, out, kB * kS, kD, kD, kD);
    }
}

// Round 13
// 638.591 us; speedup vs baseline: 1.6480x; 1.1441x over previous
//
#include <hip/hip_runtime.h>
#include <cmath>
#include <cstdint>
#include <cstddef>

namespace {
constexpr int kB = 4;
constexpr int kS = 2048;
constexpr int kD = 768;
constexpr int kH = 12;
constexpr int kHD = 64;
constexpr int k3D = 3 * kD;   // 2304
constexpr float kNeg = -1000000000.0f;
constexpr float kDelta = 0.25f;   // rescue margin >= 2 * bf16 dot error bound
}

// Faithful fp32 masking affine: s = a + NEG*(1-a), no fma contraction so the
// rounding sequence matches numpy's elementwise ops. (Identical to rounds 1-12.)
__device__ __forceinline__ float mask_affine(float a) {
#pragma clang fp contract(off)
    const float u = 1.0f - a;
    return a + kNeg * u;
}

__device__ __forceinline__ short bf16rne_s(float f) {
    uint32_t u = __builtin_bit_cast(uint32_t, f);
    u += 0x7FFFu + ((u >> 16) & 1u);
    return (short)(u >> 16);
}
__device__ __forceinline__ float bf16tof(short h) {
    const uint32_t u = ((uint32_t)(unsigned short)h) << 16;
    return __builtin_bit_cast(float, u);
}

// ---------------------------------------------------------------------------
// EXACT fp32 tiled GEMM with bias (Q,K columns — selection-critical).
// Round-13: BM=64 (TM=4) -> 1536 blocks = 6 blocks/CU = 24 waves/CU to hide
// the per-tile barrier drain. Per-output accumulation is the frozen
// k-ascending fmaf chain: retiling cannot change the result bits.
// ---------------------------------------------------------------------------
template <int BM, int BN, int BK, int TM, int TN>
__global__ __launch_bounds__(BM * BN / (TM * TN))
void gemm_bias_kernel(const float* __restrict__ A, const float* __restrict__ Bm,
                      const float* __restrict__ bias, float* __restrict__ C,
                      int M, int K, int ldb, int ldc)
{
    constexpr int THREADS = BM * BN / (TM * TN);
    constexpr int TX = BN / TN;
    constexpr int TY = THREADS / TX;
    static_assert(TX == 16 && TY * TM == BM, "geometry");
    constexpr int AF4 = BM * BK / (THREADS * 4);
    constexpr int BF4 = BK * BN / (THREADS * 4);
    constexpr int BSTR = BK * TN + 4;

    __shared__ float As[2][BK][BM + 4];
    __shared__ float Bs[2][TX][BSTR];

    const int tid = threadIdx.x;
    const int tx = tid % TX, ty = tid / TX;
    const int m0 = blockIdx.y * BM, n0 = blockIdx.x * BN;

    float4 pa[AF4], pb[BF4];
    auto load_tiles = [&](int k0) {
#pragma unroll
        for (int it = 0; it < AF4; ++it) {
            const int e = (tid + it * THREADS) * 4;
            const int row = e / BK, col = e % BK;
            pa[it] = *reinterpret_cast<const float4*>(
                &A[(size_t)(m0 + row) * K + (k0 + col)]);
        }
#pragma unroll
        for (int it = 0; it < BF4; ++it) {
            const int e = (tid + it * THREADS) * 4;
            const int row = e / BN, col = e % BN;
            pb[it] = *reinterpret_cast<const float4*>(
                &Bm[(size_t)(k0 + row) * ldb + (n0 + col)]);
        }
    };
    auto commit = [&](int buf) {
#pragma unroll
        for (int it = 0; it < AF4; ++it) {
            const int e = (tid + it * THREADS) * 4;
            const int row = e / BK, col = e % BK;
            As[buf][col + 0][row] = pa[it].x;
            As[buf][col + 1][row] = pa[it].y;
            As[buf][col + 2][row] = pa[it].z;
            As[buf][col + 3][row] = pa[it].w;
        }
#pragma unroll
        for (int it = 0; it < BF4; ++it) {
            const int e = (tid + it * THREADS) * 4;
            const int row = e / BN, col = e % BN;
            const int g = col / TN, off = col % TN;
            *reinterpret_cast<float4*>(&Bs[buf][g][row * TN + off]) = pb[it];
        }
    };

    float acc[TM][TN];
#pragma unroll
    for (int i = 0; i < TM; ++i)
#pragma unroll
        for (int j = 0; j < TN; ++j) acc[i][j] = 0.0f;

    load_tiles(0);
    commit(0);
    load_tiles(BK);
    __syncthreads();

    int cur = 0;
    for (int k0 = 0; k0 < K; k0 += BK) {
        const bool has_next = (k0 + BK < K);
        if (has_next) {
            commit(cur ^ 1);
            if (k0 + 2 * BK < K) load_tiles(k0 + 2 * BK);
        }
#pragma unroll
        for (int kk = 0; kk < BK; ++kk) {
            float a[TM], b[TN];
#pragma unroll
            for (int i = 0; i < TM; i += 4) {
                const float4 v = *reinterpret_cast<const float4*>(
                    &As[cur][kk][ty * TM + i]);
                a[i] = v.x; a[i + 1] = v.y; a[i + 2] = v.z; a[i + 3] = v.w;
            }
#pragma unroll
            for (int j = 0; j < TN; j += 4) {
                const float4 v = *reinterpret_cast<const float4*>(
                    &Bs[cur][tx][kk * TN + j]);
                b[j] = v.x; b[j + 1] = v.y; b[j + 2] = v.z; b[j + 3] = v.w;
            }
#pragma unroll
            for (int i = 0; i < TM; ++i)
#pragma unroll
                for (int j = 0; j < TN; ++j)
                    acc[i][j] = fmaf(a[i], b[j], acc[i][j]);
        }
        if (has_next) __syncthreads();
        cur ^= 1;
    }

#pragma unroll
    for (int i = 0; i < TM; ++i) {
        const int m = m0 + ty * TM + i;
#pragma unroll
        for (int j = 0; j < TN; ++j) {
            const int n = n0 + tx * TN + j;
            C[(size_t)m * ldc + n] = acc[i][j] + bias[n];
        }
    }
}

// ---------------------------------------------------------------------------
// bf16-split MFMA GEMM with bias (V projection + output projection — NOT
// selection-critical). Unchanged from round 10.
// ---------------------------------------------------------------------------
__global__ __launch_bounds__(256)
void gemm_mfma_kernel(const float* __restrict__ A, const float* __restrict__ Bm,
                      const float* __restrict__ bias, float* __restrict__ C,
                      int M, int K, int ldb, int ldc)
{
    using f32x4 = __attribute__((ext_vector_type(4))) float;
    using s16x8 = __attribute__((ext_vector_type(8))) short;
    constexpr int BM = 128, BN = 64, BK = 32;
    constexpr int AST = 40;

    __shared__ unsigned short Ah[2][BM][AST];
    __shared__ unsigned short Al[2][BM][AST];
    __shared__ unsigned short Bh[2][BN][AST];

    const int tid = threadIdx.x;
    const int wave = tid >> 6, lane = tid & 63;
    const int jq = lane & 15, hi = lane >> 4;
    const int m0 = blockIdx.y * BM, n0 = blockIdx.x * BN;

    float4 pa[4], pb[2];
    auto load_tiles = [&](int k0) {
#pragma unroll
        for (int it = 0; it < 4; ++it) {
            const int e = (tid + it * 256) * 4;
            const int row = e / BK, col = e % BK;
            pa[it] = *reinterpret_cast<const float4*>(
                &A[(size_t)(m0 + row) * K + (k0 + col)]);
        }
#pragma unroll
        for (int it = 0; it < 2; ++it) {
            const int e = (tid + it * 256) * 4;
            const int krow = e / BN, ncol = e % BN;
            pb[it] = *reinterpret_cast<const float4*>(
                &Bm[(size_t)(k0 + krow) * ldb + (n0 + ncol)]);
        }
    };
    auto commit = [&](int buf) {
#pragma unroll
        for (int it = 0; it < 4; ++it) {
            const int e = (tid + it * 256) * 4;
            const int row = e / BK, col = e % BK;
            const float v[4] = {pa[it].x, pa[it].y, pa[it].z, pa[it].w};
            ushort4 uh, ul;
            unsigned short* ph = &uh.x;
            unsigned short* pl = &ul.x;
#pragma unroll
            for (int r = 0; r < 4; ++r) {
                const short hb = bf16rne_s(v[r]);
                ph[r] = (unsigned short)hb;
                pl[r] = (unsigned short)bf16rne_s(v[r] - bf16tof(hb));
            }
            *reinterpret_cast<ushort4*>(&Ah[buf][row][col]) = uh;
            *reinterpret_cast<ushort4*>(&Al[buf][row][col]) = ul;
        }
#pragma unroll
        for (int it = 0; it < 2; ++it) {
            const int e = (tid + it * 256) * 4;
            const int krow = e / BN, ncol = e % BN;
            Bh[buf][ncol + 0][krow] = (unsigned short)bf16rne_s(pb[it].x);
            Bh[buf][ncol + 1][krow] = (unsigned short)bf16rne_s(pb[it].y);
            Bh[buf][ncol + 2][krow] = (unsigned short)bf16rne_s(pb[it].z);
            Bh[buf][ncol + 3][krow] = (unsigned short)bf16rne_s(pb[it].w);
        }
    };

    f32x4 acc[2][4];
#pragma unroll
    for (int i = 0; i < 2; ++i)
#pragma unroll
        for (int j = 0; j < 4; ++j) acc[i][j] = {0.f, 0.f, 0.f, 0.f};

    load_tiles(0);
    commit(0);
    load_tiles(BK);
    __syncthreads();

    int cur = 0;
    for (int k0 = 0; k0 < K; k0 += BK) {
        const bool has_next = (k0 + BK < K);
        if (has_next) {
            commit(cur ^ 1);
            if (k0 + 2 * BK < K) load_tiles(k0 + 2 * BK);
        }
        s16x8 ahf[2], alf[2], bhf[4];
#pragma unroll
        for (int i = 0; i < 2; ++i) {
            ahf[i] = *reinterpret_cast<const s16x8*>(
                &Ah[cur][wave * 32 + i * 16 + jq][hi * 8]);
            alf[i] = *reinterpret_cast<const s16x8*>(
                &Al[cur][wave * 32 + i * 16 + jq][hi * 8]);
        }
#pragma unroll
        for (int j = 0; j < 4; ++j)
            bhf[j] = *reinterpret_cast<const s16x8*>(
                &Bh[cur][j * 16 + jq][hi * 8]);
#pragma unroll
        for (int i = 0; i < 2; ++i)
#pragma unroll
            for (int j = 0; j < 4; ++j) {
                f32x4 c = acc[i][j];
                c = __builtin_amdgcn_mfma_f32_16x16x32_bf16(ahf[i], bhf[j], c, 0, 0, 0);
                c = __builtin_amdgcn_mfma_f32_16x16x32_bf16(alf[i], bhf[j], c, 0, 0, 0);
                acc[i][j] = c;
            }
        if (has_next) __syncthreads();
        cur ^= 1;
    }

#pragma unroll
    for (int i = 0; i < 2; ++i) {
        const int mbase = m0 + wave * 32 + i * 16 + hi * 4;
#pragma unroll
        for (int j = 0; j < 4; ++j) {
            const int n = n0 + j * 16 + jq;
            const float bv = bias[n];
#pragma unroll
            for (int r = 0; r < 4; ++r)
                C[(size_t)(mbase + r) * ldc + n] = acc[i][j][r] + bv;
        }
    }
}

// ---------------------------------------------------------------------------
// Per-key V suffix sums: vsuf[b][h][k][d] = sum_{j>=k} V[b][j][h*64+d].
// ---------------------------------------------------------------------------
__global__ __launch_bounds__(256)
void vsuf_kernel(const float* __restrict__ qkv, float* __restrict__ vsuf)
{
    const int h = blockIdx.x, b = blockIdx.y;
    const int lane = threadIdx.x & 63, wave = threadIdx.x >> 6;
    const float* vp = qkv + (size_t)b * kS * k3D + 2 * kD + h * kHD;
    float* op = vsuf + (size_t)(b * kH + h) * kS * kHD;
    __shared__ float csum[4][64];

    const int kBeg = wave * 512, kEnd = kBeg + 512;
    float s = 0.0f;
#pragma unroll 8
    for (int k = kBeg; k < kEnd; ++k)
        s += vp[(size_t)k * k3D + lane];
    csum[wave][lane] = s;
    __syncthreads();

    float run = 0.0f;
    for (int w = wave + 1; w < 4; ++w) run += csum[w][lane];
#pragma unroll 8
    for (int k = kEnd - 1; k >= kBeg; --k) {
        run += vp[(size_t)k * k3D + lane];
        op[(size_t)k * kHD + lane] = run;
    }
}

// ---------------------------------------------------------------------------
// Attention: TWO-PASS bf16-MFMA approximate scan + exact-fp32 rescue.
// Reverted to the round-10 measured-good version (attn ~165 us; selection
// bit-exact vs rounds 1-10). Single-pass variants (r11, r12) regressed:
// predicated rescue cost = (sites with >=1 active lane) x full 64-fmaf body.
// ---------------------------------------------------------------------------
__global__ __launch_bounds__(256, 4)
void attn_mfma_kernel(const float* __restrict__ qkv,
                      const float* __restrict__ vsuf,
                      float* __restrict__ ctx)
{
    using f32x4 = __attribute__((ext_vector_type(4))) float;
    using s16x8 = __attribute__((ext_vector_type(8))) short;

    const int id = blockIdx.x;
    const int bh = id % (kB * kH);
    const int t  = id / (kB * kH);
    const int b = bh / kH, h = bh % kH;

    const int tid = threadIdx.x;
    const int wave = tid >> 6, lane = tid & 63;
    const int jq = lane & 15, hi = lane >> 4;
    const int qrow = wave * 16 + jq;
    const int qglob = t * 64 + qrow;

    __shared__ float Qf[64][68];
    __shared__ float Kf[64][68];
    __shared__ float Msh[64];
    __shared__ float MgS[64];
    __shared__ int   CgS[64], I0S[64], I1S[64];

    const float* qp = qkv + (size_t)b * kS * k3D + h * kHD;
    const float* kp = qp + kD;
    const float* vp = qp + 2 * kD;

    // stage Q tile, prescaled by 0.125 (exact power of two, same as r1)
#pragma unroll
    for (int i = 0; i < 4; ++i) {
        const int f4 = tid + i * 256;
        const int r = f4 >> 4, d4 = f4 & 15;
        float4 v = *reinterpret_cast<const float4*>(
            &qp[(size_t)(t * 64 + r) * k3D + d4 * 4]);
        v.x *= 0.125f; v.y *= 0.125f; v.z *= 0.125f; v.w *= 0.125f;
        *reinterpret_cast<float4*>(&Qf[r][d4 * 4]) = v;
    }
    __syncthreads();

    auto mkfrag = [&](const float* p) {
        const float4 a = *reinterpret_cast<const float4*>(p);
        const float4 c = *reinterpret_cast<const float4*>(p + 4);
        s16x8 r;
        r[0] = bf16rne_s(a.x); r[1] = bf16rne_s(a.y);
        r[2] = bf16rne_s(a.z); r[3] = bf16rne_s(a.w);
        r[4] = bf16rne_s(c.x); r[5] = bf16rne_s(c.y);
        r[6] = bf16rne_s(c.z); r[7] = bf16rne_s(c.w);
        return r;
    };

    const s16x8 bq0 = mkfrag(&Qf[qrow][hi * 8]);
    const s16x8 bq1 = mkfrag(&Qf[qrow][32 + hi * 8]);

    auto stage_k = [&](int kt) {
#pragma unroll
        for (int i = 0; i < 4; ++i) {
            const int f4 = tid + i * 256;
            const int r = f4 >> 4, d4 = f4 & 15;
            *reinterpret_cast<float4*>(&Kf[r][d4 * 4]) =
                *reinterpret_cast<const float4*>(
                    &kp[(size_t)(kt * 64 + r) * k3D + d4 * 4]);
        }
    };

    auto score_tile = [&](f32x4* acc) {
#pragma unroll
        for (int g = 0; g < 4; ++g) {
            const s16x8 a0 = mkfrag(&Kf[g * 16 + jq][hi * 8]);
            const s16x8 a1 = mkfrag(&Kf[g * 16 + jq][32 + hi * 8]);
            f32x4 c = {0.f, 0.f, 0.f, 0.f};
            c = __builtin_amdgcn_mfma_f32_16x16x32_bf16(a0, bq0, c, 0, 0, 0);
            c = __builtin_amdgcn_mfma_f32_16x16x32_bf16(a1, bq1, c, 0, 0, 0);
            acc[g] = c;
        }
    };

    // ---- pass 1: approximate per-query causal max ----
    float mt = -INFINITY;
    for (int kt = 0; kt <= t; ++kt) {
        __syncthreads();
        stage_k(kt);
        __syncthreads();
        f32x4 acc[4];
        score_tile(acc);
#pragma unroll
        for (int g = 0; g < 4; ++g)
#pragma unroll
            for (int r = 0; r < 4; ++r) {
                const int key = kt * 64 + g * 16 + hi * 4 + r;
                if (key <= qglob) mt = fmaxf(mt, acc[g][r]);
            }
    }
    mt = fmaxf(mt, __shfl_xor(mt, 16));
    mt = fmaxf(mt, __shfl_xor(mt, 32));
    if (hi == 0) Msh[wave * 16 + jq] = mt;
    __syncthreads();
    const float thr = Msh[wave * 16 + jq] - kDelta;

    // ---- pass 2: exact rescue of candidates ----
    float m = -INFINITY;
    int cnt = 0, i0 = -1, i1 = -1;
    for (int kt = 0; kt <= t; ++kt) {
        __syncthreads();
        stage_k(kt);
        __syncthreads();
        f32x4 acc[4];
        score_tile(acc);
#pragma unroll
        for (int g = 0; g < 4; ++g)
#pragma unroll
            for (int r = 0; r < 4; ++r) {
                const int key = kt * 64 + g * 16 + hi * 4 + r;
                if (key <= qglob && acc[g][r] > thr) {
                    const float* qr = &Qf[qrow][0];
                    const float* kr = &Kf[key - kt * 64][0];
                    float dot = 0.0f;
#pragma unroll
                    for (int d4 = 0; d4 < 16; ++d4) {
                        const float4 q4 = *reinterpret_cast<const float4*>(qr + d4 * 4);
                        const float4 k4 = *reinterpret_cast<const float4*>(kr + d4 * 4);
                        dot = fmaf(q4.x, k4.x, dot);
                        dot = fmaf(q4.y, k4.y, dot);
                        dot = fmaf(q4.z, k4.z, dot);
                        dot = fmaf(q4.w, k4.w, dot);
                    }
                    const float s = mask_affine(dot);
                    const bool upd = (s > m), tie = (s == m);
                    i1 = upd ? -1 : ((tie && cnt == 1) ? key : i1);
                    i0 = upd ? key : i0;
                    cnt = upd ? 1 : (tie ? cnt + 1 : cnt);
                    m = upd ? s : m;
                }
            }
    }

    // merge the 4 lanes sharing each query column
#pragma unroll
    for (int off = 16; off <= 32; off <<= 1) {
        const float mo = __shfl_xor(m, off);
        const int co = __shfl_xor(cnt, off);
        const int o0 = __shfl_xor(i0, off);
        const int o1 = __shfl_xor(i1, off);
        if (mo > m) { m = mo; cnt = co; i0 = o0; i1 = o1; }
        else if (mo == m && co > 0) {
            if (cnt == 0) { i0 = o0; i1 = o1; }
            else if (cnt == 1) { i1 = o0; }
            cnt += co;
        }
    }
    if (hi == 0) {
        MgS[wave * 16 + jq] = m; CgS[wave * 16 + jq] = cnt;
        I0S[wave * 16 + jq] = i0; I1S[wave * 16 + jq] = i1;
    }
    __syncthreads();

    // ---- epilogue: 4 threads per query, 16 dims each ----
    const int qloc = tid >> 2, qtr = tid & 3;
    const int qi = t * 64 + qloc;
    float mg = MgS[qloc];
    int fcnt = CgS[qloc], f0 = I0S[qloc], f1 = I1S[qloc];

    bool addsuf = false;
    if (qi < kS - 1) {
        const bool lt = (mg < kNeg), eq = (mg == kNeg);
        if (lt)      { fcnt = kS - 1 - qi; f0 = -1; f1 = -1; addsuf = true; }
        else if (eq) { fcnt += kS - 1 - qi; addsuf = true; }
    }

    float4 a4[4];
#pragma unroll
    for (int i = 0; i < 4; ++i) a4[i] = {0.f, 0.f, 0.f, 0.f};

    if (f0 >= 0) {
        const float* vr = vp + (size_t)f0 * k3D + qtr * 16;
#pragma unroll
        for (int i = 0; i < 4; ++i) {
            const float4 v = *reinterpret_cast<const float4*>(vr + i * 4);
            a4[i].x += v.x; a4[i].y += v.y; a4[i].z += v.z; a4[i].w += v.w;
        }
    }
    if (f1 >= 0) {
        const float* vr = vp + (size_t)f1 * k3D + qtr * 16;
#pragma unroll
        for (int i = 0; i < 4; ++i) {
            const float4 v = *reinterpret_cast<const float4*>(vr + i * 4);
            a4[i].x += v.x; a4[i].y += v.y; a4[i].z += v.z; a4[i].w += v.w;
        }
    }
    if (addsuf) {
        const float* sp = vsuf + ((size_t)(b * kH + h) * kS + (qi + 1)) * kHD
                          + qtr * 16;
#pragma unroll
        for (int i = 0; i < 4; ++i) {
            const float4 v = *reinterpret_cast<const float4*>(sp + i * 4);
            a4[i].x += v.x; a4[i].y += v.y; a4[i].z += v.z; a4[i].w += v.w;
        }
    }

    float* op = ctx + ((size_t)b * kS + qi) * kD + h * kHD + qtr * 16;
    const float fc = (float)fcnt;
#pragma unroll
    for (int i = 0; i < 4; ++i) {
        const float4 r = {a4[i].x / fc, a4[i].y / fc, a4[i].z / fc, a4[i].w / fc};
        *reinterpret_cast<float4*>(op + i * 4) = r;
    }
}

// ---------------------------------------------------------------------------
extern "C" void kernel_launch(void* const* d_in, const int* in_sizes, int n_in,
                              void* d_out, int out_size, void* d_ws, size_t ws_size,
                              hipStream_t stream)
{
    const float* x     = (const float*)d_in[0];
    const float* W_qkv = (const float*)d_in[1];
    const float* b_qkv = (const float*)d_in[2];
    const float* W_o   = (const float*)d_in[3];
    const float* b_o   = (const float*)d_in[4];
    float* out = (float*)d_out;

    // workspace: qkv [8192][2304] (75.5 MB) + ctx [8192][768] (25 MB).
    // vsuf (25.2 MB) lives in d_out, fully overwritten by the final GEMM.
    float* qkv  = (float*)d_ws;
    float* ctx  = qkv + (size_t)kB * kS * k3D;
    float* vsuf = out;

    // 1a) Q,K columns: EXACT fp32 GEMM (selection-critical, chain frozen)
    //     BM=64 -> 1536 blocks (6/CU) for barrier-stall hiding.
    {
        dim3 grid(1536 / 128, (kB * kS) / 64);
        gemm_bias_kernel<64, 128, 16, 4, 8><<<grid, 256, 0, stream>>>(
            x, W_qkv, b_qkv, qkv, kB * kS, kD, k3D, k3D);
    }
    // 1b) V columns: staged-split bf16 MFMA GEMM (not selection-critical)
    {
        dim3 grid(kD / 64, (kB * kS) / 128);
        gemm_mfma_kernel<<<grid, 256, 0, stream>>>(
            x, W_qkv + 2 * kD, b_qkv + 2 * kD, qkv + 2 * kD,
            kB * kS, kD, k3D, k3D);
    }
    // 1c) per-key V suffix sums (for the all-masked-dominated rows)
    {
        dim3 grid(kH, kB);
        vsuf_kernel<<<grid, 256, 0, stream>>>(qkv, vsuf);
    }
    // 2) attention: two-pass MFMA approx scan + exact fp32 rescue
    //    (selection identical to rounds 1-10)
    {
        attn_mfma_kernel<<<dim3((kS / 64) * kB * kH), 256, 0, stream>>>(
            qkv, vsuf, ctx);
    }
    // 3) out = ctx @ W_o + b_o : staged-split bf16 MFMA GEMM
    {
        dim3 grid(kD / 64, (kB * kS) / 128);
        gemm_mfma_kernel<<<grid, 256, 0, stream>>>(
            ctx, W_o, b_o, out, kB * kS, kD, kD, kD);
    }
}

// Round 14
// 575.787 us; speedup vs baseline: 1.8277x; 1.1091x over previous
//
#include <hip/hip_runtime.h>
#include <cmath>
#include <cstdint>
#include <cstddef>

namespace {
constexpr int kB = 4;
constexpr int kS = 2048;
constexpr int kD = 768;
constexpr int kH = 12;
constexpr int kHD = 64;
constexpr int k3D = 3 * kD;   // 2304
constexpr float kNeg = -1000000000.0f;
constexpr float kDelta = 0.25f;   // rescue margin >= 2 * bf16 dot error bound
}

// Faithful fp32 masking affine: s = a + NEG*(1-a), no fma contraction so the
// rounding sequence matches numpy's elementwise ops. (Identical to rounds 1-13.)
__device__ __forceinline__ float mask_affine(float a) {
#pragma clang fp contract(off)
    const float u = 1.0f - a;
    return a + kNeg * u;
}

__device__ __forceinline__ short bf16rne_s(float f) {
    uint32_t u = __builtin_bit_cast(uint32_t, f);
    u += 0x7FFFu + ((u >> 16) & 1u);
    return (short)(u >> 16);
}
__device__ __forceinline__ float bf16tof(short h) {
    const uint32_t u = ((uint32_t)(unsigned short)h) << 16;
    return __builtin_bit_cast(float, u);
}

// ---------------------------------------------------------------------------
// EXACT fp32 tiled GEMM with bias (Q,K columns — selection-critical).
// r10 measured-best geometry: 256 threads, 8x8 microtile, BK=16, dbuf, one
// barrier per K-tile. LDS-BW-bound at ~67% VALU ceiling (r13 post-mortem);
// frozen k-ascending fmaf chain per output — bit-identical across rounds.
// ---------------------------------------------------------------------------
template <int BM, int BN, int BK, int TM, int TN>
__global__ __launch_bounds__(BM * BN / (TM * TN))
void gemm_bias_kernel(const float* __restrict__ A, const float* __restrict__ Bm,
                      const float* __restrict__ bias, float* __restrict__ C,
                      int M, int K, int ldb, int ldc)
{
    constexpr int THREADS = BM * BN / (TM * TN);
    constexpr int TX = BN / TN;
    constexpr int TY = THREADS / TX;
    static_assert(TX == 16 && TY * TM == BM, "geometry");
    constexpr int AF4 = BM * BK / (THREADS * 4);
    constexpr int BF4 = BK * BN / (THREADS * 4);
    constexpr int BSTR = BK * TN + 4;

    __shared__ float As[2][BK][BM + 4];
    __shared__ float Bs[2][TX][BSTR];

    const int tid = threadIdx.x;
    const int tx = tid % TX, ty = tid / TX;
    const int m0 = blockIdx.y * BM, n0 = blockIdx.x * BN;

    float4 pa[AF4], pb[BF4];
    auto load_tiles = [&](int k0) {
#pragma unroll
        for (int it = 0; it < AF4; ++it) {
            const int e = (tid + it * THREADS) * 4;
            const int row = e / BK, col = e % BK;
            pa[it] = *reinterpret_cast<const float4*>(
                &A[(size_t)(m0 + row) * K + (k0 + col)]);
        }
#pragma unroll
        for (int it = 0; it < BF4; ++it) {
            const int e = (tid + it * THREADS) * 4;
            const int row = e / BN, col = e % BN;
            pb[it] = *reinterpret_cast<const float4*>(
                &Bm[(size_t)(k0 + row) * ldb + (n0 + col)]);
        }
    };
    auto commit = [&](int buf) {
#pragma unroll
        for (int it = 0; it < AF4; ++it) {
            const int e = (tid + it * THREADS) * 4;
            const int row = e / BK, col = e % BK;
            As[buf][col + 0][row] = pa[it].x;
            As[buf][col + 1][row] = pa[it].y;
            As[buf][col + 2][row] = pa[it].z;
            As[buf][col + 3][row] = pa[it].w;
        }
#pragma unroll
        for (int it = 0; it < BF4; ++it) {
            const int e = (tid + it * THREADS) * 4;
            const int row = e / BN, col = e % BN;
            const int g = col / TN, off = col % TN;
            *reinterpret_cast<float4*>(&Bs[buf][g][row * TN + off]) = pb[it];
        }
    };

    float acc[TM][TN];
#pragma unroll
    for (int i = 0; i < TM; ++i)
#pragma unroll
        for (int j = 0; j < TN; ++j) acc[i][j] = 0.0f;

    load_tiles(0);
    commit(0);
    load_tiles(BK);
    __syncthreads();

    int cur = 0;
    for (int k0 = 0; k0 < K; k0 += BK) {
        const bool has_next = (k0 + BK < K);
        if (has_next) {
            commit(cur ^ 1);
            if (k0 + 2 * BK < K) load_tiles(k0 + 2 * BK);
        }
#pragma unroll
        for (int kk = 0; kk < BK; ++kk) {
            float a[TM], b[TN];
#pragma unroll
            for (int i = 0; i < TM; i += 4) {
                const float4 v = *reinterpret_cast<const float4*>(
                    &As[cur][kk][ty * TM + i]);
                a[i] = v.x; a[i + 1] = v.y; a[i + 2] = v.z; a[i + 3] = v.w;
            }
#pragma unroll
            for (int j = 0; j < TN; j += 4) {
                const float4 v = *reinterpret_cast<const float4*>(
                    &Bs[cur][tx][kk * TN + j]);
                b[j] = v.x; b[j + 1] = v.y; b[j + 2] = v.z; b[j + 3] = v.w;
            }
#pragma unroll
            for (int i = 0; i < TM; ++i)
#pragma unroll
                for (int j = 0; j < TN; ++j)
                    acc[i][j] = fmaf(a[i], b[j], acc[i][j]);
        }
        if (has_next) __syncthreads();
        cur ^= 1;
    }

#pragma unroll
    for (int i = 0; i < TM; ++i) {
        const int m = m0 + ty * TM + i;
#pragma unroll
        for (int j = 0; j < TN; ++j) {
            const int n = n0 + tx * TN + j;
            C[(size_t)m * ldc + n] = acc[i][j] + bias[n];
        }
    }
}

// ---------------------------------------------------------------------------
// bf16-split MFMA GEMM with bias (V projection + output projection — NOT
// selection-critical). Unchanged from round 10.
// ---------------------------------------------------------------------------
__global__ __launch_bounds__(256)
void gemm_mfma_kernel(const float* __restrict__ A, const float* __restrict__ Bm,
                      const float* __restrict__ bias, float* __restrict__ C,
                      int M, int K, int ldb, int ldc)
{
    using f32x4 = __attribute__((ext_vector_type(4))) float;
    using s16x8 = __attribute__((ext_vector_type(8))) short;
    constexpr int BM = 128, BN = 64, BK = 32;
    constexpr int AST = 40;

    __shared__ unsigned short Ah[2][BM][AST];
    __shared__ unsigned short Al[2][BM][AST];
    __shared__ unsigned short Bh[2][BN][AST];

    const int tid = threadIdx.x;
    const int wave = tid >> 6, lane = tid & 63;
    const int jq = lane & 15, hi = lane >> 4;
    const int m0 = blockIdx.y * BM, n0 = blockIdx.x * BN;

    float4 pa[4], pb[2];
    auto load_tiles = [&](int k0) {
#pragma unroll
        for (int it = 0; it < 4; ++it) {
            const int e = (tid + it * 256) * 4;
            const int row = e / BK, col = e % BK;
            pa[it] = *reinterpret_cast<const float4*>(
                &A[(size_t)(m0 + row) * K + (k0 + col)]);
        }
#pragma unroll
        for (int it = 0; it < 2; ++it) {
            const int e = (tid + it * 256) * 4;
            const int krow = e / BN, ncol = e % BN;
            pb[it] = *reinterpret_cast<const float4*>(
                &Bm[(size_t)(k0 + krow) * ldb + (n0 + ncol)]);
        }
    };
    auto commit = [&](int buf) {
#pragma unroll
        for (int it = 0; it < 4; ++it) {
            const int e = (tid + it * 256) * 4;
            const int row = e / BK, col = e % BK;
            const float v[4] = {pa[it].x, pa[it].y, pa[it].z, pa[it].w};
            ushort4 uh, ul;
            unsigned short* ph = &uh.x;
            unsigned short* pl = &ul.x;
#pragma unroll
            for (int r = 0; r < 4; ++r) {
                const short hb = bf16rne_s(v[r]);
                ph[r] = (unsigned short)hb;
                pl[r] = (unsigned short)bf16rne_s(v[r] - bf16tof(hb));
            }
            *reinterpret_cast<ushort4*>(&Ah[buf][row][col]) = uh;
            *reinterpret_cast<ushort4*>(&Al[buf][row][col]) = ul;
        }
#pragma unroll
        for (int it = 0; it < 2; ++it) {
            const int e = (tid + it * 256) * 4;
            const int krow = e / BN, ncol = e % BN;
            Bh[buf][ncol + 0][krow] = (unsigned short)bf16rne_s(pb[it].x);
            Bh[buf][ncol + 1][krow] = (unsigned short)bf16rne_s(pb[it].y);
            Bh[buf][ncol + 2][krow] = (unsigned short)bf16rne_s(pb[it].z);
            Bh[buf][ncol + 3][krow] = (unsigned short)bf16rne_s(pb[it].w);
        }
    };

    f32x4 acc[2][4];
#pragma unroll
    for (int i = 0; i < 2; ++i)
#pragma unroll
        for (int j = 0; j < 4; ++j) acc[i][j] = {0.f, 0.f, 0.f, 0.f};

    load_tiles(0);
    commit(0);
    load_tiles(BK);
    __syncthreads();

    int cur = 0;
    for (int k0 = 0; k0 < K; k0 += BK) {
        const bool has_next = (k0 + BK < K);
        if (has_next) {
            commit(cur ^ 1);
            if (k0 + 2 * BK < K) load_tiles(k0 + 2 * BK);
        }
        s16x8 ahf[2], alf[2], bhf[4];
#pragma unroll
        for (int i = 0; i < 2; ++i) {
            ahf[i] = *reinterpret_cast<const s16x8*>(
                &Ah[cur][wave * 32 + i * 16 + jq][hi * 8]);
            alf[i] = *reinterpret_cast<const s16x8*>(
                &Al[cur][wave * 32 + i * 16 + jq][hi * 8]);
        }
#pragma unroll
        for (int j = 0; j < 4; ++j)
            bhf[j] = *reinterpret_cast<const s16x8*>(
                &Bh[cur][j * 16 + jq][hi * 8]);
#pragma unroll
        for (int i = 0; i < 2; ++i)
#pragma unroll
            for (int j = 0; j < 4; ++j) {
                f32x4 c = acc[i][j];
                c = __builtin_amdgcn_mfma_f32_16x16x32_bf16(ahf[i], bhf[j], c, 0, 0, 0);
                c = __builtin_amdgcn_mfma_f32_16x16x32_bf16(alf[i], bhf[j], c, 0, 0, 0);
                acc[i][j] = c;
            }
        if (has_next) __syncthreads();
        cur ^= 1;
    }

#pragma unroll
    for (int i = 0; i < 2; ++i) {
        const int mbase = m0 + wave * 32 + i * 16 + hi * 4;
#pragma unroll
        for (int j = 0; j < 4; ++j) {
            const int n = n0 + j * 16 + jq;
            const float bv = bias[n];
#pragma unroll
            for (int r = 0; r < 4; ++r)
                C[(size_t)(mbase + r) * ldc + n] = acc[i][j][r] + bv;
        }
    }
}

// ---------------------------------------------------------------------------
// Per-key V suffix sums: vsuf[b][h][k][d] = sum_{j>=k} V[b][j][h*64+d].
// ---------------------------------------------------------------------------
__global__ __launch_bounds__(256)
void vsuf_kernel(const float* __restrict__ qkv, float* __restrict__ vsuf)
{
    const int h = blockIdx.x, b = blockIdx.y;
    const int lane = threadIdx.x & 63, wave = threadIdx.x >> 6;
    const float* vp = qkv + (size_t)b * kS * k3D + 2 * kD + h * kHD;
    float* op = vsuf + (size_t)(b * kH + h) * kS * kHD;
    __shared__ float csum[4][64];

    const int kBeg = wave * 512, kEnd = kBeg + 512;
    float s = 0.0f;
#pragma unroll 8
    for (int k = kBeg; k < kEnd; ++k)
        s += vp[(size_t)k * k3D + lane];
    csum[wave][lane] = s;
    __syncthreads();

    float run = 0.0f;
    for (int w = wave + 1; w < 4; ++w) run += csum[w][lane];
#pragma unroll 8
    for (int k = kEnd - 1; k >= kBeg; --k) {
        run += vp[(size_t)k * k3D + lane];
        op[(size_t)k * kHD + lane] = run;
    }
}

// ---------------------------------------------------------------------------
// Attention: TWO-PASS bf16-MFMA approximate scan + exact-fp32 rescue.
// Round-14 change (selection-preserving): K converted to bf16 ONCE at staging
// into Kb[64][72] (144B rows, 16B-aligned fragments); score_tile is now pure
// ds_read_b128 + MFMA (was ~224 convert-VALU/lane/tile — the measured
// bottleneck: VALUBusy 48%, MfmaUtil 1.5%). Pass 1 stages Kb only; pass 2
// stages Kb + the fp32 Kf so the exact rescue still reads BIT-IDENTICAL fp32
// K from LDS (r8's regression was global-memory rescue, not staging-convert).
// Approx scores identical across passes (same Kb, same bq) => candidate
// superset logic intact; rescue chain unchanged => selection bit-exact r1-r13.
// ---------------------------------------------------------------------------
__global__ __launch_bounds__(256, 3)
void attn_mfma_kernel(const float* __restrict__ qkv,
                      const float* __restrict__ vsuf,
                      float* __restrict__ ctx)
{
    using f32x4 = __attribute__((ext_vector_type(4))) float;
    using s16x8 = __attribute__((ext_vector_type(8))) short;

    const int id = blockIdx.x;
    const int bh = id % (kB * kH);
    const int t  = id / (kB * kH);
    const int b = bh / kH, h = bh % kH;

    const int tid = threadIdx.x;
    const int wave = tid >> 6, lane = tid & 63;
    const int jq = lane & 15, hi = lane >> 4;
    const int qrow = wave * 16 + jq;
    const int qglob = t * 64 + qrow;

    __shared__ float Qf[64][68];
    __shared__ float Kf[64][68];
    __shared__ unsigned short Kb[64][72];
    __shared__ float Msh[64];
    __shared__ float MgS[64];
    __shared__ int   CgS[64], I0S[64], I1S[64];

    const float* qp = qkv + (size_t)b * kS * k3D + h * kHD;
    const float* kp = qp + kD;
    const float* vp = qp + 2 * kD;

    // stage Q tile, prescaled by 0.125 (exact power of two, same as r1)
#pragma unroll
    for (int i = 0; i < 4; ++i) {
        const int f4 = tid + i * 256;
        const int r = f4 >> 4, d4 = f4 & 15;
        float4 v = *reinterpret_cast<const float4*>(
            &qp[(size_t)(t * 64 + r) * k3D + d4 * 4]);
        v.x *= 0.125f; v.y *= 0.125f; v.z *= 0.125f; v.w *= 0.125f;
        *reinterpret_cast<float4*>(&Qf[r][d4 * 4]) = v;
    }
    __syncthreads();

    auto mkfrag = [&](const float* p) {
        const float4 a = *reinterpret_cast<const float4*>(p);
        const float4 c = *reinterpret_cast<const float4*>(p + 4);
        s16x8 r;
        r[0] = bf16rne_s(a.x); r[1] = bf16rne_s(a.y);
        r[2] = bf16rne_s(a.z); r[3] = bf16rne_s(a.w);
        r[4] = bf16rne_s(c.x); r[5] = bf16rne_s(c.y);
        r[6] = bf16rne_s(c.z); r[7] = bf16rne_s(c.w);
        return r;
    };

    const s16x8 bq0 = mkfrag(&Qf[qrow][hi * 8]);
    const s16x8 bq1 = mkfrag(&Qf[qrow][32 + hi * 8]);

    // stage one K tile as bf16 only (pass 1)
    auto stage_kb = [&](int kt) {
#pragma unroll
        for (int i = 0; i < 4; ++i) {
            const int f4 = tid + i * 256;
            const int r = f4 >> 4, d4 = f4 & 15;
            const float4 v = *reinterpret_cast<const float4*>(
                &kp[(size_t)(kt * 64 + r) * k3D + d4 * 4]);
            ushort4 u;
            u.x = (unsigned short)bf16rne_s(v.x);
            u.y = (unsigned short)bf16rne_s(v.y);
            u.z = (unsigned short)bf16rne_s(v.z);
            u.w = (unsigned short)bf16rne_s(v.w);
            *reinterpret_cast<ushort4*>(&Kb[r][d4 * 4]) = u;
        }
    };
    // stage K tile as bf16 AND fp32 (pass 2: fp32 needed for exact rescue)
    auto stage_both = [&](int kt) {
#pragma unroll
        for (int i = 0; i < 4; ++i) {
            const int f4 = tid + i * 256;
            const int r = f4 >> 4, d4 = f4 & 15;
            const float4 v = *reinterpret_cast<const float4*>(
                &kp[(size_t)(kt * 64 + r) * k3D + d4 * 4]);
            *reinterpret_cast<float4*>(&Kf[r][d4 * 4]) = v;
            ushort4 u;
            u.x = (unsigned short)bf16rne_s(v.x);
            u.y = (unsigned short)bf16rne_s(v.y);
            u.z = (unsigned short)bf16rne_s(v.z);
            u.w = (unsigned short)bf16rne_s(v.w);
            *reinterpret_cast<ushort4*>(&Kb[r][d4 * 4]) = u;
        }
    };

    auto score_tile = [&](f32x4* acc) {
#pragma unroll
        for (int g = 0; g < 4; ++g) {
            const s16x8 a0 = *reinterpret_cast<const s16x8*>(
                &Kb[g * 16 + jq][hi * 8]);
            const s16x8 a1 = *reinterpret_cast<const s16x8*>(
                &Kb[g * 16 + jq][32 + hi * 8]);
            f32x4 c = {0.f, 0.f, 0.f, 0.f};
            c = __builtin_amdgcn_mfma_f32_16x16x32_bf16(a0, bq0, c, 0, 0, 0);
            c = __builtin_amdgcn_mfma_f32_16x16x32_bf16(a1, bq1, c, 0, 0, 0);
            acc[g] = c;
        }
    };

    // ---- pass 1: approximate per-query causal max (bf16 tiles only) ----
    float mt = -INFINITY;
    for (int kt = 0; kt <= t; ++kt) {
        __syncthreads();
        stage_kb(kt);
        __syncthreads();
        f32x4 acc[4];
        score_tile(acc);
#pragma unroll
        for (int g = 0; g < 4; ++g)
#pragma unroll
            for (int r = 0; r < 4; ++r) {
                const int key = kt * 64 + g * 16 + hi * 4 + r;
                if (key <= qglob) mt = fmaxf(mt, acc[g][r]);
            }
    }
    mt = fmaxf(mt, __shfl_xor(mt, 16));
    mt = fmaxf(mt, __shfl_xor(mt, 32));
    if (hi == 0) Msh[wave * 16 + jq] = mt;
    __syncthreads();
    const float thr = Msh[wave * 16 + jq] - kDelta;

    // ---- pass 2: exact rescue of candidates (fp32 chain from LDS Kf) ----
    float m = -INFINITY;
    int cnt = 0, i0 = -1, i1 = -1;
    for (int kt = 0; kt <= t; ++kt) {
        __syncthreads();
        stage_both(kt);
        __syncthreads();
        f32x4 acc[4];
        score_tile(acc);
#pragma unroll
        for (int g = 0; g < 4; ++g)
#pragma unroll
            for (int r = 0; r < 4; ++r) {
                const int key = kt * 64 + g * 16 + hi * 4 + r;
                if (key <= qglob && acc[g][r] > thr) {
                    const float* qr = &Qf[qrow][0];
                    const float* kr = &Kf[key - kt * 64][0];
                    float dot = 0.0f;
#pragma unroll
                    for (int d4 = 0; d4 < 16; ++d4) {
                        const float4 q4 = *reinterpret_cast<const float4*>(qr + d4 * 4);
                        const float4 k4 = *reinterpret_cast<const float4*>(kr + d4 * 4);
                        dot = fmaf(q4.x, k4.x, dot);
                        dot = fmaf(q4.y, k4.y, dot);
                        dot = fmaf(q4.z, k4.z, dot);
                        dot = fmaf(q4.w, k4.w, dot);
                    }
                    const float s = mask_affine(dot);
                    const bool upd = (s > m), tie = (s == m);
                    i1 = upd ? -1 : ((tie && cnt == 1) ? key : i1);
                    i0 = upd ? key : i0;
                    cnt = upd ? 1 : (tie ? cnt + 1 : cnt);
                    m = upd ? s : m;
                }
            }
    }

    // merge the 4 lanes sharing each query column
#pragma unroll
    for (int off = 16; off <= 32; off <<= 1) {
        const float mo = __shfl_xor(m, off);
        const int co = __shfl_xor(cnt, off);
        const int o0 = __shfl_xor(i0, off);
        const int o1 = __shfl_xor(i1, off);
        if (mo > m) { m = mo; cnt = co; i0 = o0; i1 = o1; }
        else if (mo == m && co > 0) {
            if (cnt == 0) { i0 = o0; i1 = o1; }
            else if (cnt == 1) { i1 = o0; }
            cnt += co;
        }
    }
    if (hi == 0) {
        MgS[wave * 16 + jq] = m; CgS[wave * 16 + jq] = cnt;
        I0S[wave * 16 + jq] = i0; I1S[wave * 16 + jq] = i1;
    }
    __syncthreads();

    // ---- epilogue: 4 threads per query, 16 dims each ----
    const int qloc = tid >> 2, qtr = tid & 3;
    const int qi = t * 64 + qloc;
    float mg = MgS[qloc];
    int fcnt = CgS[qloc], f0 = I0S[qloc], f1 = I1S[qloc];

    bool addsuf = false;
    if (qi < kS - 1) {
        const bool lt = (mg < kNeg), eq = (mg == kNeg);
        if (lt)      { fcnt = kS - 1 - qi; f0 = -1; f1 = -1; addsuf = true; }
        else if (eq) { fcnt += kS - 1 - qi; addsuf = true; }
    }

    float4 a4[4];
#pragma unroll
    for (int i = 0; i < 4; ++i) a4[i] = {0.f, 0.f, 0.f, 0.f};

    if (f0 >= 0) {
        const float* vr = vp + (size_t)f0 * k3D + qtr * 16;
#pragma unroll
        for (int i = 0; i < 4; ++i) {
            const float4 v = *reinterpret_cast<const float4*>(vr + i * 4);
            a4[i].x += v.x; a4[i].y += v.y; a4[i].z += v.z; a4[i].w += v.w;
        }
    }
    if (f1 >= 0) {
        const float* vr = vp + (size_t)f1 * k3D + qtr * 16;
#pragma unroll
        for (int i = 0; i < 4; ++i) {
            const float4 v = *reinterpret_cast<const float4*>(vr + i * 4);
            a4[i].x += v.x; a4[i].y += v.y; a4[i].z += v.z; a4[i].w += v.w;
        }
    }
    if (addsuf) {
        const float* sp = vsuf + ((size_t)(b * kH + h) * kS + (qi + 1)) * kHD
                          + qtr * 16;
#pragma unroll
        for (int i = 0; i < 4; ++i) {
            const float4 v = *reinterpret_cast<const float4*>(sp + i * 4);
            a4[i].x += v.x; a4[i].y += v.y; a4[i].z += v.z; a4[i].w += v.w;
        }
    }

    float* op = ctx + ((size_t)b * kS + qi) * kD + h * kHD + qtr * 16;
    const float fc = (float)fcnt;
#pragma unroll
    for (int i = 0; i < 4; ++i) {
        const float4 r = {a4[i].x / fc, a4[i].y / fc, a4[i].z / fc, a4[i].w / fc};
        *reinterpret_cast<float4*>(op + i * 4) = r;
    }
}

// ---------------------------------------------------------------------------
extern "C" void kernel_launch(void* const* d_in, const int* in_sizes, int n_in,
                              void* d_out, int out_size, void* d_ws, size_t ws_size,
                              hipStream_t stream)
{
    const float* x     = (const float*)d_in[0];
    const float* W_qkv = (const float*)d_in[1];
    const float* b_qkv = (const float*)d_in[2];
    const float* W_o   = (const float*)d_in[3];
    const float* b_o   = (const float*)d_in[4];
    float* out = (float*)d_out;

    // workspace: qkv [8192][2304] (75.5 MB) + ctx [8192][768] (25 MB).
    // vsuf (25.2 MB) lives in d_out, fully overwritten by the final GEMM.
    float* qkv  = (float*)d_ws;
    float* ctx  = qkv + (size_t)kB * kS * k3D;
    float* vsuf = out;

    // 1a) Q,K columns: EXACT fp32 GEMM (selection-critical, chain frozen)
    //     r10 measured-best geometry: 256 threads, 8x8 microtile, BM=128.
    {
        dim3 grid(1536 / 128, (kB * kS) / 128);
        gemm_bias_kernel<128, 128, 16, 8, 8><<<grid, 256, 0, stream>>>(
            x, W_qkv, b_qkv, qkv, kB * kS, kD, k3D, k3D);
    }
    // 1b) V columns: staged-split bf16 MFMA GEMM (not selection-critical)
    {
        dim3 grid(kD / 64, (kB * kS) / 128);
        gemm_mfma_kernel<<<grid, 256, 0, stream>>>(
            x, W_qkv + 2 * kD, b_qkv + 2 * kD, qkv + 2 * kD,
            kB * kS, kD, k3D, k3D);
    }
    // 1c) per-key V suffix sums (for the all-masked-dominated rows)
    {
        dim3 grid(kH, kB);
        vsuf_kernel<<<grid, 256, 0, stream>>>(qkv, vsuf);
    }
    // 2) attention: two-pass MFMA approx scan (bf16-at-staging) + exact fp32
    //    rescue from LDS (selection identical to rounds 1-13)
    {
        attn_mfma_kernel<<<dim3((kS / 64) * kB * kH), 256, 0, stream>>>(
            qkv, vsuf, ctx);
    }
    // 3) out = ctx @ W_o + b_o : staged-split bf16 MFMA GEMM
    {
        dim3 grid(kD / 64, (kB * kS) / 128);
        gemm_mfma_kernel<<<grid, 256, 0, stream>>>(
            ctx, W_o, b_o, out, kB * kS, kD, kD, kD);
    }
}